// Round 3
// baseline (2940.820 us; speedup 1.0000x reference)
//
#include <hip/hip_runtime.h>

typedef unsigned short u16;
typedef __attribute__((ext_vector_type(4))) unsigned short u16x4;
typedef __attribute__((ext_vector_type(4))) float f32x4;
typedef __attribute__((ext_vector_type(8))) __bf16 bf16x8;

#define NN 16000
#define NE 64000

__device__ __forceinline__ float bf2f(u16 b) {
  union { unsigned int u; float f; } v; v.u = ((unsigned int)b) << 16; return v.f;
}
__device__ __forceinline__ u16 f2bf(float x) {
  union { float f; unsigned int u; } v; v.f = x;
  unsigned int r = v.u + 0x7FFFu + ((v.u >> 16) & 1u);
  return (u16)(r >> 16);
}

// ---------------- init: f32 -> f32 working copy + bf16 mirror ----------------
__global__ void cast_init(const float* __restrict__ in, float* __restrict__ outf,
                          u16* __restrict__ outb, int n4) {
  for (int i = blockIdx.x * blockDim.x + threadIdx.x; i < n4; i += gridDim.x * blockDim.x) {
    f32x4 v = ((const f32x4*)in)[i];
    u16x4 b;
#pragma unroll
    for (int j = 0; j < 4; ++j) b[j] = f2bf(v[j]);
    ((f32x4*)outf)[i] = v;
    ((u16x4*)outb)[i] = b;
  }
}

// ---- weight transpose + bf16 cast: WT[n][k] = bf16(W[k][c0+n]), 4 matrices in z ----
__global__ void transpose4(const float* __restrict__ W0, const float* __restrict__ W1,
                           const float* __restrict__ W2, const float* __restrict__ W3,
                           int ld, int c0, u16* __restrict__ WT) {
  __shared__ float t[16][17];
  int z = blockIdx.z;
  const float* W = z == 0 ? W0 : (z == 1 ? W1 : (z == 2 ? W2 : W3));
  u16* O = WT + (size_t)z * 65536;
  int n0 = blockIdx.x * 16, k0 = blockIdx.y * 16;
  int tx = threadIdx.x, ty = threadIdx.y;
  t[ty][tx] = W[(size_t)(k0 + ty) * ld + c0 + n0 + tx];
  __syncthreads();
  O[(size_t)(n0 + ty) * 256 + k0 + tx] = f2bf(t[tx][ty]);
}

// ---------------- bf16 GEMM: C[M,256] = A[M,256] @ B, B given transposed ----------------
// grid = (M/128, 2, nmat); 128x128 tile, 4 waves, each wave 64x64 via 4x4 16x16x32 MFMA frags.
__global__ __launch_bounds__(256) void gemm_abt(
    const u16* __restrict__ A,
    const u16* __restrict__ BT0, const u16* __restrict__ BT1, const u16* __restrict__ BT2,
    u16* __restrict__ C0, u16* __restrict__ C1, u16* __restrict__ C2) {
  const int bz = blockIdx.z;
  const u16* BT = bz == 0 ? BT0 : (bz == 1 ? BT1 : BT2);
  u16* C = bz == 0 ? C0 : (bz == 1 ? C1 : C2);
  const int m0 = blockIdx.x * 128;
  const int n0 = blockIdx.y * 128;
  __shared__ u16 lA[128 * 64];
  __shared__ u16 lB[128 * 64];
  const int tid = threadIdx.x;
  const int lane = tid & 63;
  const int wid = tid >> 6;
  const int wr = (wid >> 1) * 64;
  const int wc = (wid & 1) * 64;
  f32x4 acc[4][4] = {};
  for (int k0 = 0; k0 < 256; k0 += 64) {
#pragma unroll
    for (int i = 0; i < 4; ++i) {
      const int lb = tid * 16 + i * 4096;   // byte offset in 16KB tile
      const int row = lb >> 7;              // 128B per row (64 cols bf16)
      const int cole = (lb & 127) >> 1;     // element col
      __builtin_amdgcn_global_load_lds(
          (const __attribute__((address_space(1))) void*)(A + (size_t)(m0 + row) * 256 + k0 + cole),
          (__attribute__((address_space(3))) void*)((char*)lA + lb), 16, 0, 0);
      __builtin_amdgcn_global_load_lds(
          (const __attribute__((address_space(1))) void*)(BT + (size_t)(n0 + row) * 256 + k0 + cole),
          (__attribute__((address_space(3))) void*)((char*)lB + lb), 16, 0, 0);
    }
    __syncthreads();
#pragma unroll
    for (int kk = 0; kk < 2; ++kk) {
      bf16x8 af[4], bfr[4];
#pragma unroll
      for (int m = 0; m < 4; ++m)
        af[m] = *(const bf16x8*)(lA + (wr + m * 16 + (lane & 15)) * 64 + kk * 32 + (lane >> 4) * 8);
#pragma unroll
      for (int n = 0; n < 4; ++n)
        bfr[n] = *(const bf16x8*)(lB + (wc + n * 16 + (lane & 15)) * 64 + kk * 32 + (lane >> 4) * 8);
#pragma unroll
      for (int m = 0; m < 4; ++m)
#pragma unroll
        for (int n = 0; n < 4; ++n)
          acc[m][n] = __builtin_amdgcn_mfma_f32_16x16x32_bf16(af[m], bfr[n], acc[m][n], 0, 0, 0);
    }
    __syncthreads();
  }
  const int cr = (lane >> 4) * 4;  // C/D: col = lane&15, row = (lane>>4)*4 + reg (verified layout)
  const int cc = lane & 15;
#pragma unroll
  for (int m = 0; m < 4; ++m)
#pragma unroll
    for (int n = 0; n < 4; ++n) {
      size_t base = (size_t)(m0 + wr + m * 16 + cr) * 256 + (n0 + wc + n * 16 + cc);
#pragma unroll
      for (int j = 0; j < 4; ++j)
        C[base + (size_t)j * 256] = f2bf(acc[m][n][j]);
    }
}

// ---- hidden-layer edge pass: f_out, f-state residual (f32, in d_out), bf16 mirror, logits, denom ----
__global__ __launch_bounds__(256) void edge_hidden(
    const u16* __restrict__ t_ni, const u16* __restrict__ t_nj, const u16* __restrict__ fW,
    const int* __restrict__ src, const int* __restrict__ dst,
    const float* __restrict__ bias, const float* __restrict__ attn,
    float* __restrict__ f_cur, u16* __restrict__ f_bf,
    float* __restrict__ exb, float* __restrict__ sb) {
  int e = blockIdx.x * 4 + (threadIdx.x >> 6);
  if (e >= NE) return;
  int lane = threadIdx.x & 63;
  int is = src[e], id = dst[e];
  int c = lane * 4;
  u16x4 va = *(const u16x4*)(t_ni + (size_t)is * 256 + c);
  u16x4 vb = *(const u16x4*)(t_nj + (size_t)id * 256 + c);
  u16x4 vc = *(const u16x4*)(fW + (size_t)e * 256 + c);
  f32x4 vbi = *(const f32x4*)(bias + c);
  int h = lane >> 3;
  f32x4 vat = *(const f32x4*)(attn + h * 32 + (lane & 7) * 4);
  size_t idx0 = (size_t)e * 256 + c;
  f32x4 fc = *(f32x4*)(f_cur + idx0);
  float part = 0.f;
  u16x4 fb;
#pragma unroll
  for (int j = 0; j < 4; ++j) {
    float y = bf2f(va[j]) + bf2f(vb[j]) + bf2f(vc[j]) + vbi[j];
    y = y > 0.f ? y : 0.01f * y;           // leaky_relu
    part += y * vat[j];                    // attention logit partial
    float el = y > 0.f ? y : expm1f(y);    // elu(f_out)
    fc[j] += el;
    fb[j] = f2bf(fc[j]);
  }
  *(f32x4*)(f_cur + idx0) = fc;
  *(u16x4*)(f_bf + idx0) = fb;
  part += __shfl_xor(part, 1);
  part += __shfl_xor(part, 2);
  part += __shfl_xor(part, 4);             // reduce the 8 lanes of this head
  part = fminf(fmaxf(part, -30.f), 30.f);  // insurance: exp can never overflow
  float ev = expf(part);
  if ((lane & 7) == 0) {
    exb[(size_t)e * 8 + h] = ev;
    atomicAdd(&sb[(size_t)id * 8 + h], ev);
  }
}

// ---------------- hidden-layer message scatter ----------------
__global__ __launch_bounds__(256) void edge_msg_hidden(
    const u16* __restrict__ t_node, const int* __restrict__ src, const int* __restrict__ dst,
    const float* __restrict__ exb, const float* __restrict__ sb, float* __restrict__ h_out) {
  int e = blockIdx.x * 4 + (threadIdx.x >> 6);
  if (e >= NE) return;
  int lane = threadIdx.x & 63;
  int is = src[e], id = dst[e];
  int h = lane >> 3;
  float a = exb[(size_t)e * 8 + h] / sb[(size_t)id * 8 + h];
  int c = lane * 4;
  u16x4 hv = *(const u16x4*)(t_node + (size_t)is * 256 + c);
#pragma unroll
  for (int j = 0; j < 4; ++j)
    atomicAdd(&h_out[(size_t)id * 256 + c + j], a * bf2f(hv[j]));
}

// ---------------- node residual update: n_cur += elu(h_out), refresh bf16 mirror ----------------
__global__ void node_update(float* __restrict__ n_cur, const float* __restrict__ h_out,
                            u16* __restrict__ n_bf, int n4) {
  for (int i = blockIdx.x * blockDim.x + threadIdx.x; i < n4; i += gridDim.x * blockDim.x) {
    f32x4 hv = ((const f32x4*)h_out)[i];
    f32x4 nv = ((f32x4*)n_cur)[i];
    u16x4 bv;
#pragma unroll
    for (int j = 0; j < 4; ++j) {
      float t = hv[j];
      t = t > 0.f ? t : expm1f(t);
      nv[j] += t;
      bv[j] = f2bf(nv[j]);
    }
    ((f32x4*)n_cur)[i] = nv;
    ((u16x4*)n_bf)[i] = bv;
  }
}

// ---- final-layer edge pass (one head): out_f += y/8 (f32, in d_out), logits, denom ----
__global__ __launch_bounds__(256) void edge_final(
    const u16* __restrict__ t_ni, const u16* __restrict__ t_nj, const u16* __restrict__ fW,
    const int* __restrict__ src, const int* __restrict__ dst,
    const float* __restrict__ bias, const float* __restrict__ attn,
    float* __restrict__ out_f, float* __restrict__ exb, float* __restrict__ sb) {
  int e = blockIdx.x * 4 + (threadIdx.x >> 6);
  if (e >= NE) return;
  int lane = threadIdx.x & 63;
  int is = src[e], id = dst[e];
  int c = lane * 4;
  u16x4 va = *(const u16x4*)(t_ni + (size_t)is * 256 + c);
  u16x4 vb = *(const u16x4*)(t_nj + (size_t)id * 256 + c);
  u16x4 vc = *(const u16x4*)(fW + (size_t)e * 256 + c);
  f32x4 vbi = *(const f32x4*)(bias + c);
  f32x4 vat = *(const f32x4*)(attn + c);
  size_t idx0 = (size_t)e * 256 + c;
  f32x4 fo = *(f32x4*)(out_f + idx0);
  float part = 0.f;
#pragma unroll
  for (int j = 0; j < 4; ++j) {
    float y = bf2f(va[j]) + bf2f(vb[j]) + bf2f(vc[j]) + vbi[j];
    y = y > 0.f ? y : 0.01f * y;     // leaky_relu; final layer: head-mean, no elu
    part += y * vat[j];
    fo[j] += 0.125f * y;
  }
  *(f32x4*)(out_f + idx0) = fo;
#pragma unroll
  for (int m = 1; m < 64; m <<= 1) part += __shfl_xor(part, m);  // full 256-dot reduce
  part = fminf(fmaxf(part, -30.f), 30.f);
  float ev = expf(part);
  if (lane == 0) {
    exb[e] = ev;
    atomicAdd(&sb[id], ev);
  }
}

// ---------------- final-layer message scatter (one head, 1/8 for head mean) ----------------
__global__ __launch_bounds__(256) void edge_msg_final(
    const u16* __restrict__ t_node, const int* __restrict__ src, const int* __restrict__ dst,
    const float* __restrict__ exb, const float* __restrict__ sb, float* __restrict__ h_out) {
  int e = blockIdx.x * 4 + (threadIdx.x >> 6);
  if (e >= NE) return;
  int lane = threadIdx.x & 63;
  int is = src[e], id = dst[e];
  float a = exb[e] / sb[id] * 0.125f;
  int c = lane * 4;
  u16x4 hv = *(const u16x4*)(t_node + (size_t)is * 256 + c);
#pragma unroll
  for (int j = 0; j < 4; ++j)
    atomicAdd(&h_out[(size_t)id * 256 + c + j], a * bf2f(hv[j]));
}

// ---------------- out_n = n_cur + h_out (f32) ----------------
__global__ void store_n(const float* __restrict__ n_cur, const float* __restrict__ h_out,
                        float* __restrict__ out, int n4) {
  for (int i = blockIdx.x * blockDim.x + threadIdx.x; i < n4; i += gridDim.x * blockDim.x) {
    f32x4 av = ((const f32x4*)n_cur)[i];
    f32x4 bv = ((const f32x4*)h_out)[i];
#pragma unroll
    for (int j = 0; j < 4; ++j) av[j] += bv[j];
    ((f32x4*)out)[i] = av;
  }
}

extern "C" void kernel_launch(void* const* d_in, const int* in_sizes, int n_in,
                              void* d_out, int out_size, void* d_ws, size_t ws_size,
                              hipStream_t stream) {
  const float* nfeat   = (const float*)d_in[0];
  const float* efeat   = (const float*)d_in[1];
  const int*   src     = (const int*)d_in[2];
  const int*   dst     = (const int*)d_in[3];
  const float* Wnode_h = (const float*)d_in[4];
  const float* Wni_h   = (const float*)d_in[5];
  const float* Wnj_h   = (const float*)d_in[6];
  const float* Wfij_h  = (const float*)d_in[7];
  const float* attn_h  = (const float*)d_in[8];
  const float* bias_h  = (const float*)d_in[9];
  const float* Wnode_l = (const float*)d_in[10];
  const float* Wni_l   = (const float*)d_in[11];
  const float* Wnj_l   = (const float*)d_in[12];
  const float* Wfij_l  = (const float*)d_in[13];
  const float* attn_l  = (const float*)d_in[14];
  const float* bias_l  = (const float*)d_in[15];

  // workspace layout — total ~134 MB (edge f32 state lives in d_out's f region)
  char* ws = (char*)d_ws;
  size_t off = 0;
  auto alloc = [&](size_t b) { char* p = ws + off; off += (b + 255) & ~(size_t)255; return p; };
  float* n_cur = (float*)alloc((size_t)NN * 256 * 4);   // node state (f32)
  u16* n_bf    = (u16*)alloc((size_t)NN * 256 * 2);     // bf16 mirror (GEMM A)
  u16* f_bf    = (u16*)alloc((size_t)NE * 256 * 2);
  u16* t_ni    = (u16*)alloc((size_t)NN * 256 * 2);     // GEMM outputs (bf16)
  u16* t_nj    = (u16*)alloc((size_t)NN * 256 * 2);
  u16* t_node  = (u16*)alloc((size_t)NN * 256 * 2);
  u16* fW      = (u16*)alloc((size_t)NE * 256 * 2);
  float* exb   = (float*)alloc((size_t)NE * 8 * 4);     // exp(logits)
  float* sb    = (float*)alloc((size_t)NN * 8 * 4);     // softmax denominators
  float* h_out = (float*)alloc((size_t)NN * 256 * 4);   // attention output accumulator (f32)
  u16* WT      = (u16*)alloc((size_t)4 * 65536 * 2);    // transposed bf16 weight slices
  u16* WT_node = WT;
  u16* WT_ni   = WT + 65536;
  u16* WT_nj   = WT + 2 * 65536;
  u16* WT_fij  = WT + 3 * 65536;

  float* out_n = (float*)d_out;
  float* out_f = out_n + (size_t)NN * 256;   // running f32 edge state AND final f output

  cast_init<<<1024, 256, 0, stream>>>(nfeat, n_cur, n_bf, NN * 256 / 4);
  cast_init<<<2048, 256, 0, stream>>>(efeat, out_f, f_bf, NE * 256 / 4);

  for (int l = 0; l < 2; ++l) {
    transpose4<<<dim3(16, 16, 4), dim3(16, 16), 0, stream>>>(
        Wnode_h + (size_t)l * 65536, Wni_h + (size_t)l * 65536,
        Wnj_h + (size_t)l * 65536, Wfij_h + (size_t)l * 65536, 256, 0, WT);
    hipMemsetAsync(sb, 0, (size_t)NN * 8 * 4, stream);
    hipMemsetAsync(h_out, 0, (size_t)NN * 256 * 4, stream);
    gemm_abt<<<dim3(125, 2, 3), 256, 0, stream>>>(n_bf, WT_ni, WT_nj, WT_node, t_ni, t_nj, t_node);
    gemm_abt<<<dim3(500, 2, 1), 256, 0, stream>>>(f_bf, WT_fij, WT_fij, WT_fij, fW, fW, fW);
    edge_hidden<<<16000, 256, 0, stream>>>(t_ni, t_nj, fW, src, dst,
        bias_h + (size_t)l * 256, attn_h + (size_t)l * 256, out_f, f_bf, exb, sb);
    edge_msg_hidden<<<16000, 256, 0, stream>>>(t_node, src, dst, exb, sb, h_out);
    node_update<<<1024, 256, 0, stream>>>(n_cur, h_out, n_bf, NN * 256 / 4);
  }

  // final layer: per-head; f head-mean accumulates directly into out_f (which holds f state)
  hipMemsetAsync(sb, 0, (size_t)NN * 8 * 4, stream);
  hipMemsetAsync(h_out, 0, (size_t)NN * 256 * 4, stream);
  for (int h = 0; h < 8; ++h) {
    transpose4<<<dim3(16, 16, 4), dim3(16, 16), 0, stream>>>(
        Wnode_l, Wni_l, Wnj_l, Wfij_l, 2048, h * 256, WT);
    gemm_abt<<<dim3(125, 2, 3), 256, 0, stream>>>(n_bf, WT_ni, WT_nj, WT_node, t_ni, t_nj, t_node);
    gemm_abt<<<dim3(500, 2, 1), 256, 0, stream>>>(f_bf, WT_fij, WT_fij, WT_fij, fW, fW, fW);
    edge_final<<<16000, 256, 0, stream>>>(t_ni, t_nj, fW, src, dst,
        bias_l + (size_t)h * 256, attn_l + (size_t)h * 256, out_f, exb, sb + (size_t)h * NN);
    edge_msg_final<<<16000, 256, 0, stream>>>(t_node, src, dst, exb, sb + (size_t)h * NN, h_out);
  }

  store_n<<<1024, 256, 0, stream>>>(n_cur, h_out, out_n, NN * 256 / 4);
}

// Round 4
// 940.765 us; speedup vs baseline: 3.1260x; 3.1260x over previous
//
#include <hip/hip_runtime.h>

typedef unsigned short u16;
typedef __attribute__((ext_vector_type(4))) unsigned short u16x4;
typedef __attribute__((ext_vector_type(4))) float f32x4;
typedef __attribute__((ext_vector_type(8))) __bf16 bf16x8;

#define NN 16000
#define NE 64000

__device__ __forceinline__ float bf2f(u16 b) {
  union { unsigned int u; float f; } v; v.u = ((unsigned int)b) << 16; return v.f;
}
__device__ __forceinline__ u16 f2bf(float x) {
  union { float f; unsigned int u; } v; v.f = x;
  unsigned int r = v.u + 0x7FFFu + ((v.u >> 16) & 1u);
  return (u16)(r >> 16);
}

// ---------------- init: f32 -> f32 working copy + bf16 mirror ----------------
__global__ void cast_init(const float* __restrict__ in, float* __restrict__ outf,
                          u16* __restrict__ outb, int n4) {
  for (int i = blockIdx.x * blockDim.x + threadIdx.x; i < n4; i += gridDim.x * blockDim.x) {
    f32x4 v = ((const f32x4*)in)[i];
    u16x4 b;
#pragma unroll
    for (int j = 0; j < 4; ++j) b[j] = f2bf(v[j]);
    ((f32x4*)outf)[i] = v;
    ((u16x4*)outb)[i] = b;
  }
}

// ---------------- CSR build: degree histogram ----------------
__global__ void deg_hist(const int* __restrict__ dst, int* __restrict__ deg) {
  int e = blockIdx.x * 256 + threadIdx.x;
  if (e < NE) atomicAdd(&deg[dst[e]], 1);
}

// ---- single-block scan: row_ptr = exclusive_scan(deg), cursor = copy (16000 < 1024*16) ----
__global__ __launch_bounds__(1024) void scan_deg(const int* __restrict__ deg,
                                                 int* __restrict__ row_ptr,
                                                 int* __restrict__ cursor) {
  __shared__ int lds[1024];
  int t = threadIdx.x;
  int base = t * 16;
  int v[16];
  int s = 0;
#pragma unroll
  for (int j = 0; j < 16; ++j) {
    int idx = base + j;
    v[j] = idx < NN ? deg[idx] : 0;
    s += v[j];
  }
  lds[t] = s;
  __syncthreads();
  for (int d = 1; d < 1024; d <<= 1) {
    int x = t >= d ? lds[t - d] : 0;
    __syncthreads();
    lds[t] += x;
    __syncthreads();
  }
  int run = lds[t] - s;  // exclusive prefix
  for (int j = 0; j < 16; ++j) {
    int idx = base + j;
    if (idx < NN) { row_ptr[idx] = run; cursor[idx] = run; run += v[j]; }
  }
  if (t == 1023) row_ptr[NN] = run;  // == total edge count
}

// ---------------- CSR fill: bucket edges by dst ----------------
__global__ void csr_fill(const int* __restrict__ src, const int* __restrict__ dst,
                         int* __restrict__ cursor, int* __restrict__ cs_e,
                         int* __restrict__ cs_src) {
  int e = blockIdx.x * 256 + threadIdx.x;
  if (e >= NE) return;
  int pos = atomicAdd(&cursor[dst[e]], 1);
  cs_e[pos] = e;
  cs_src[pos] = src[e];
}

// ---- weight transpose + bf16 cast: WT[n][k] = bf16(W[k][c0+n]), 4 matrices in z ----
__global__ void transpose4(const float* __restrict__ W0, const float* __restrict__ W1,
                           const float* __restrict__ W2, const float* __restrict__ W3,
                           int ld, int c0, u16* __restrict__ WT) {
  __shared__ float t[16][17];
  int z = blockIdx.z;
  const float* W = z == 0 ? W0 : (z == 1 ? W1 : (z == 2 ? W2 : W3));
  u16* O = WT + (size_t)z * 65536;
  int n0 = blockIdx.x * 16, k0 = blockIdx.y * 16;
  int tx = threadIdx.x, ty = threadIdx.y;
  t[ty][tx] = W[(size_t)(k0 + ty) * ld + c0 + n0 + tx];
  __syncthreads();
  O[(size_t)(n0 + ty) * 256 + k0 + tx] = f2bf(t[tx][ty]);
}

// ---------------- bf16 GEMM: C[M,256] = A[M,256] @ B, B given transposed ----------------
__global__ __launch_bounds__(256) void gemm_abt(
    const u16* __restrict__ A,
    const u16* __restrict__ BT0, const u16* __restrict__ BT1, const u16* __restrict__ BT2,
    u16* __restrict__ C0, u16* __restrict__ C1, u16* __restrict__ C2) {
  const int bz = blockIdx.z;
  const u16* BT = bz == 0 ? BT0 : (bz == 1 ? BT1 : BT2);
  u16* C = bz == 0 ? C0 : (bz == 1 ? C1 : C2);
  const int m0 = blockIdx.x * 128;
  const int n0 = blockIdx.y * 128;
  __shared__ u16 lA[128 * 64];
  __shared__ u16 lB[128 * 64];
  const int tid = threadIdx.x;
  const int lane = tid & 63;
  const int wid = tid >> 6;
  const int wr = (wid >> 1) * 64;
  const int wc = (wid & 1) * 64;
  f32x4 acc[4][4] = {};
  for (int k0 = 0; k0 < 256; k0 += 64) {
#pragma unroll
    for (int i = 0; i < 4; ++i) {
      const int lb = tid * 16 + i * 4096;
      const int row = lb >> 7;
      const int cole = (lb & 127) >> 1;
      __builtin_amdgcn_global_load_lds(
          (const __attribute__((address_space(1))) void*)(A + (size_t)(m0 + row) * 256 + k0 + cole),
          (__attribute__((address_space(3))) void*)((char*)lA + lb), 16, 0, 0);
      __builtin_amdgcn_global_load_lds(
          (const __attribute__((address_space(1))) void*)(BT + (size_t)(n0 + row) * 256 + k0 + cole),
          (__attribute__((address_space(3))) void*)((char*)lB + lb), 16, 0, 0);
    }
    __syncthreads();
#pragma unroll
    for (int kk = 0; kk < 2; ++kk) {
      bf16x8 af[4], bfr[4];
#pragma unroll
      for (int m = 0; m < 4; ++m)
        af[m] = *(const bf16x8*)(lA + (wr + m * 16 + (lane & 15)) * 64 + kk * 32 + (lane >> 4) * 8);
#pragma unroll
      for (int n = 0; n < 4; ++n)
        bfr[n] = *(const bf16x8*)(lB + (wc + n * 16 + (lane & 15)) * 64 + kk * 32 + (lane >> 4) * 8);
#pragma unroll
      for (int m = 0; m < 4; ++m)
#pragma unroll
        for (int n = 0; n < 4; ++n)
          acc[m][n] = __builtin_amdgcn_mfma_f32_16x16x32_bf16(af[m], bfr[n], acc[m][n], 0, 0, 0);
    }
    __syncthreads();
  }
  const int cr = (lane >> 4) * 4;
  const int cc = lane & 15;
#pragma unroll
  for (int m = 0; m < 4; ++m)
#pragma unroll
    for (int n = 0; n < 4; ++n) {
      size_t base = (size_t)(m0 + wr + m * 16 + cr) * 256 + (n0 + wc + n * 16 + cc);
#pragma unroll
      for (int j = 0; j < 4; ++j)
        C[base + (size_t)j * 256] = f2bf(acc[m][n][j]);
    }
}

// ---- hidden-layer edge pass: f_out, f-state residual (f32), bf16 mirror, logits ----
__global__ __launch_bounds__(256) void edge_hidden(
    const u16* __restrict__ t_ni, const u16* __restrict__ t_nj, const u16* __restrict__ fW,
    const int* __restrict__ src, const int* __restrict__ dst,
    const float* __restrict__ bias, const float* __restrict__ attn,
    float* __restrict__ f_cur, u16* __restrict__ f_bf, float* __restrict__ exb) {
  int e = blockIdx.x * 4 + (threadIdx.x >> 6);
  if (e >= NE) return;
  int lane = threadIdx.x & 63;
  int is = src[e], id = dst[e];
  int c = lane * 4;
  u16x4 va = *(const u16x4*)(t_ni + (size_t)is * 256 + c);
  u16x4 vb = *(const u16x4*)(t_nj + (size_t)id * 256 + c);
  u16x4 vc = *(const u16x4*)(fW + (size_t)e * 256 + c);
  f32x4 vbi = *(const f32x4*)(bias + c);
  int h = lane >> 3;
  f32x4 vat = *(const f32x4*)(attn + h * 32 + (lane & 7) * 4);
  size_t idx0 = (size_t)e * 256 + c;
  f32x4 fc = *(f32x4*)(f_cur + idx0);
  float part = 0.f;
  u16x4 fb;
#pragma unroll
  for (int j = 0; j < 4; ++j) {
    float y = bf2f(va[j]) + bf2f(vb[j]) + bf2f(vc[j]) + vbi[j];
    y = y > 0.f ? y : 0.01f * y;           // leaky_relu
    part += y * vat[j];                    // attention logit partial
    float el = y > 0.f ? y : expm1f(y);    // elu(f_out)
    fc[j] += el;
    fb[j] = f2bf(fc[j]);
  }
  *(f32x4*)(f_cur + idx0) = fc;
  *(u16x4*)(f_bf + idx0) = fb;
  part += __shfl_xor(part, 1);
  part += __shfl_xor(part, 2);
  part += __shfl_xor(part, 4);             // reduce the 8 lanes of this head
  part = fminf(fmaxf(part, -30.f), 30.f);  // insurance: exp can never overflow
  if ((lane & 7) == 0) exb[(size_t)e * 8 + h] = expf(part);
}

// ---- hidden gather: per-node softmax denom + weighted message sum + elu + residual ----
// one wave per node; lane covers 4 floats, head = lane>>3. No atomics.
__global__ __launch_bounds__(256) void node_gather_hidden(
    const u16* __restrict__ t_node, const int* __restrict__ row_ptr,
    const int* __restrict__ cs_e, const int* __restrict__ cs_src,
    const float* __restrict__ exb, float* __restrict__ n_cur, u16* __restrict__ n_bf) {
  int node = blockIdx.x * 4 + (threadIdx.x >> 6);
  if (node >= NN) return;
  int lane = threadIdx.x & 63;
  int c = lane * 4, h = lane >> 3;
  int beg = row_ptr[node], end = row_ptr[node + 1];
  float denom = 0.f;
  float acc[4] = {0.f, 0.f, 0.f, 0.f};
  for (int p = beg; p < end; ++p) {
    float a = exb[(size_t)cs_e[p] * 8 + h];
    denom += a;
    u16x4 hv = *(const u16x4*)(t_node + (size_t)cs_src[p] * 256 + c);
#pragma unroll
    for (int j = 0; j < 4; ++j) acc[j] += a * bf2f(hv[j]);
  }
  float inv = denom > 0.f ? 1.f / denom : 0.f;  // deg-0 node: message = 0
  size_t i0 = (size_t)node * 256 + c;
  f32x4 nv = *(f32x4*)(n_cur + i0);
  u16x4 bv;
#pragma unroll
  for (int j = 0; j < 4; ++j) {
    float t = acc[j] * inv;
    t = t > 0.f ? t : expm1f(t);   // elu
    nv[j] += t;
    bv[j] = f2bf(nv[j]);
  }
  *(f32x4*)(n_cur + i0) = nv;
  *(u16x4*)(n_bf + i0) = bv;
}

// ---- final-layer edge pass (one head): out_f += y/8 (f32), logit ----
__global__ __launch_bounds__(256) void edge_final(
    const u16* __restrict__ t_ni, const u16* __restrict__ t_nj, const u16* __restrict__ fW,
    const int* __restrict__ src, const int* __restrict__ dst,
    const float* __restrict__ bias, const float* __restrict__ attn,
    float* __restrict__ out_f, float* __restrict__ exb) {
  int e = blockIdx.x * 4 + (threadIdx.x >> 6);
  if (e >= NE) return;
  int lane = threadIdx.x & 63;
  int is = src[e], id = dst[e];
  int c = lane * 4;
  u16x4 va = *(const u16x4*)(t_ni + (size_t)is * 256 + c);
  u16x4 vb = *(const u16x4*)(t_nj + (size_t)id * 256 + c);
  u16x4 vc = *(const u16x4*)(fW + (size_t)e * 256 + c);
  f32x4 vbi = *(const f32x4*)(bias + c);
  f32x4 vat = *(const f32x4*)(attn + c);
  size_t idx0 = (size_t)e * 256 + c;
  f32x4 fo = *(f32x4*)(out_f + idx0);
  float part = 0.f;
#pragma unroll
  for (int j = 0; j < 4; ++j) {
    float y = bf2f(va[j]) + bf2f(vb[j]) + bf2f(vc[j]) + vbi[j];
    y = y > 0.f ? y : 0.01f * y;   // leaky_relu; final layer: head-mean, no elu
    part += y * vat[j];
    fo[j] += 0.125f * y;
  }
  *(f32x4*)(out_f + idx0) = fo;
#pragma unroll
  for (int m = 1; m < 64; m <<= 1) part += __shfl_xor(part, m);  // full 256-dot reduce
  part = fminf(fmaxf(part, -30.f), 30.f);
  if (lane == 0) exb[e] = expf(part);
}

// ---- final gather (one head): h_out += (1/8) * softmax-weighted message sum ----
__global__ __launch_bounds__(256) void node_gather_final(
    const u16* __restrict__ t_node, const int* __restrict__ row_ptr,
    const int* __restrict__ cs_e, const int* __restrict__ cs_src,
    const float* __restrict__ exb, float* __restrict__ h_out) {
  int node = blockIdx.x * 4 + (threadIdx.x >> 6);
  if (node >= NN) return;
  int lane = threadIdx.x & 63;
  int c = lane * 4;
  int beg = row_ptr[node], end = row_ptr[node + 1];
  float denom = 0.f;
  float acc[4] = {0.f, 0.f, 0.f, 0.f};
  for (int p = beg; p < end; ++p) {
    float a = exb[cs_e[p]];
    denom += a;
    u16x4 hv = *(const u16x4*)(t_node + (size_t)cs_src[p] * 256 + c);
#pragma unroll
    for (int j = 0; j < 4; ++j) acc[j] += a * bf2f(hv[j]);
  }
  float inv = denom > 0.f ? 0.125f / denom : 0.f;
  size_t i0 = (size_t)node * 256 + c;
  f32x4 ho = *(f32x4*)(h_out + i0);
#pragma unroll
  for (int j = 0; j < 4; ++j) ho[j] += acc[j] * inv;
  *(f32x4*)(h_out + i0) = ho;
}

// ---------------- out_n = n_cur + h_out (f32) ----------------
__global__ void store_n(const float* __restrict__ n_cur, const float* __restrict__ h_out,
                        float* __restrict__ out, int n4) {
  for (int i = blockIdx.x * blockDim.x + threadIdx.x; i < n4; i += gridDim.x * blockDim.x) {
    f32x4 av = ((const f32x4*)n_cur)[i];
    f32x4 bv = ((const f32x4*)h_out)[i];
#pragma unroll
    for (int j = 0; j < 4; ++j) av[j] += bv[j];
    ((f32x4*)out)[i] = av;
  }
}

extern "C" void kernel_launch(void* const* d_in, const int* in_sizes, int n_in,
                              void* d_out, int out_size, void* d_ws, size_t ws_size,
                              hipStream_t stream) {
  const float* nfeat   = (const float*)d_in[0];
  const float* efeat   = (const float*)d_in[1];
  const int*   src     = (const int*)d_in[2];
  const int*   dst     = (const int*)d_in[3];
  const float* Wnode_h = (const float*)d_in[4];
  const float* Wni_h   = (const float*)d_in[5];
  const float* Wnj_h   = (const float*)d_in[6];
  const float* Wfij_h  = (const float*)d_in[7];
  const float* attn_h  = (const float*)d_in[8];
  const float* bias_h  = (const float*)d_in[9];
  const float* Wnode_l = (const float*)d_in[10];
  const float* Wni_l   = (const float*)d_in[11];
  const float* Wnj_l   = (const float*)d_in[12];
  const float* Wfij_l  = (const float*)d_in[13];
  const float* attn_l  = (const float*)d_in[14];
  const float* bias_l  = (const float*)d_in[15];

  // workspace layout — ~136 MB (f32 edge state lives in d_out's f region)
  char* ws = (char*)d_ws;
  size_t off = 0;
  auto alloc = [&](size_t b) { char* p = ws + off; off += (b + 255) & ~(size_t)255; return p; };
  float* n_cur = (float*)alloc((size_t)NN * 256 * 4);   // node state (f32)
  u16* n_bf    = (u16*)alloc((size_t)NN * 256 * 2);     // bf16 mirror (GEMM A)
  u16* f_bf    = (u16*)alloc((size_t)NE * 256 * 2);
  u16* t_ni    = (u16*)alloc((size_t)NN * 256 * 2);     // GEMM outputs (bf16)
  u16* t_nj    = (u16*)alloc((size_t)NN * 256 * 2);
  u16* t_node  = (u16*)alloc((size_t)NN * 256 * 2);
  u16* fW      = (u16*)alloc((size_t)NE * 256 * 2);
  float* exb   = (float*)alloc((size_t)NE * 8 * 4);     // exp(logits)
  float* h_out = (float*)alloc((size_t)NN * 256 * 4);   // final-layer node accumulator (f32)
  u16* WT      = (u16*)alloc((size_t)4 * 65536 * 2);    // transposed bf16 weight slices
  int* deg     = (int*)alloc((size_t)NN * 4);           // CSR
  int* cursor  = (int*)alloc((size_t)NN * 4);
  int* row_ptr = (int*)alloc((size_t)(NN + 1) * 4);
  int* cs_e    = (int*)alloc((size_t)NE * 4);
  int* cs_src  = (int*)alloc((size_t)NE * 4);
  u16* WT_node = WT;
  u16* WT_ni   = WT + 65536;
  u16* WT_nj   = WT + 2 * 65536;
  u16* WT_fij  = WT + 3 * 65536;

  float* out_n = (float*)d_out;
  float* out_f = out_n + (size_t)NN * 256;   // running f32 edge state AND final f output

  // CSR build (reused by all 10 message passes)
  hipMemsetAsync(deg, 0, (size_t)NN * 4, stream);
  deg_hist<<<(NE + 255) / 256, 256, 0, stream>>>(dst, deg);
  scan_deg<<<1, 1024, 0, stream>>>(deg, row_ptr, cursor);
  csr_fill<<<(NE + 255) / 256, 256, 0, stream>>>(src, dst, cursor, cs_e, cs_src);

  cast_init<<<1024, 256, 0, stream>>>(nfeat, n_cur, n_bf, NN * 256 / 4);
  cast_init<<<2048, 256, 0, stream>>>(efeat, out_f, f_bf, NE * 256 / 4);

  for (int l = 0; l < 2; ++l) {
    transpose4<<<dim3(16, 16, 4), dim3(16, 16), 0, stream>>>(
        Wnode_h + (size_t)l * 65536, Wni_h + (size_t)l * 65536,
        Wnj_h + (size_t)l * 65536, Wfij_h + (size_t)l * 65536, 256, 0, WT);
    gemm_abt<<<dim3(125, 2, 3), 256, 0, stream>>>(n_bf, WT_ni, WT_nj, WT_node, t_ni, t_nj, t_node);
    gemm_abt<<<dim3(500, 2, 1), 256, 0, stream>>>(f_bf, WT_fij, WT_fij, WT_fij, fW, fW, fW);
    edge_hidden<<<16000, 256, 0, stream>>>(t_ni, t_nj, fW, src, dst,
        bias_h + (size_t)l * 256, attn_h + (size_t)l * 256, out_f, f_bf, exb);
    node_gather_hidden<<<4000, 256, 0, stream>>>(t_node, row_ptr, cs_e, cs_src, exb, n_cur, n_bf);
  }

  // final layer: per-head; f head-mean accumulates directly into out_f (holds f state)
  hipMemsetAsync(h_out, 0, (size_t)NN * 256 * 4, stream);
  for (int h = 0; h < 8; ++h) {
    transpose4<<<dim3(16, 16, 4), dim3(16, 16), 0, stream>>>(
        Wnode_l, Wni_l, Wnj_l, Wfij_l, 2048, h * 256, WT);
    gemm_abt<<<dim3(125, 2, 3), 256, 0, stream>>>(n_bf, WT_ni, WT_nj, WT_node, t_ni, t_nj, t_node);
    gemm_abt<<<dim3(500, 2, 1), 256, 0, stream>>>(f_bf, WT_fij, WT_fij, WT_fij, fW, fW, fW);
    edge_final<<<16000, 256, 0, stream>>>(t_ni, t_nj, fW, src, dst,
        bias_l + (size_t)h * 256, attn_l + (size_t)h * 256, out_f, exb);
    node_gather_final<<<4000, 256, 0, stream>>>(t_node, row_ptr, cs_e, cs_src, exb, h_out);
  }

  store_n<<<1024, 256, 0, stream>>>(n_cur, h_out, out_n, NN * 256 / 4);
}

// Round 5
// 901.884 us; speedup vs baseline: 3.2608x; 1.0431x over previous
//
#include <hip/hip_runtime.h>

typedef unsigned short u16;
typedef __attribute__((ext_vector_type(4))) unsigned short u16x4;
typedef __attribute__((ext_vector_type(4))) float f32x4;
typedef __attribute__((ext_vector_type(8))) __bf16 bf16x8;

#define NN 16000
#define NE 64000

__device__ __forceinline__ float bf2f(u16 b) {
  union { unsigned int u; float f; } v; v.u = ((unsigned int)b) << 16; return v.f;
}
__device__ __forceinline__ u16 f2bf(float x) {
  union { float f; unsigned int u; } v; v.f = x;
  unsigned int r = v.u + 0x7FFFu + ((v.u >> 16) & 1u);
  return (u16)(r >> 16);
}

// ---------------- node init: f32 working copy + bf16 mirror ----------------
__global__ void cast_init(const float* __restrict__ in, float* __restrict__ outf,
                          u16* __restrict__ outb, int n4) {
  for (int i = blockIdx.x * blockDim.x + threadIdx.x; i < n4; i += gridDim.x * blockDim.x) {
    f32x4 v = ((const f32x4*)in)[i];
    u16x4 b;
#pragma unroll
    for (int j = 0; j < 4; ++j) b[j] = f2bf(v[j]);
    ((f32x4*)outf)[i] = v;
    ((u16x4*)outb)[i] = b;
  }
}

// ---------------- edge init: bf16 mirror only (f-state lives in bf16) ----------------
__global__ void cast_bf(const float* __restrict__ in, u16* __restrict__ outb, int n4) {
  for (int i = blockIdx.x * blockDim.x + threadIdx.x; i < n4; i += gridDim.x * blockDim.x) {
    f32x4 v = ((const f32x4*)in)[i];
    u16x4 b;
#pragma unroll
    for (int j = 0; j < 4; ++j) b[j] = f2bf(v[j]);
    ((u16x4*)outb)[i] = b;
  }
}

// ---------------- CSR build ----------------
__global__ void deg_hist(const int* __restrict__ dst, int* __restrict__ deg) {
  int e = blockIdx.x * 256 + threadIdx.x;
  if (e < NE) atomicAdd(&deg[dst[e]], 1);
}

__global__ __launch_bounds__(1024) void scan_deg(const int* __restrict__ deg,
                                                 int* __restrict__ row_ptr,
                                                 int* __restrict__ cursor) {
  __shared__ int lds[1024];
  int t = threadIdx.x;
  int base = t * 16;
  int v[16];
  int s = 0;
#pragma unroll
  for (int j = 0; j < 16; ++j) {
    int idx = base + j;
    v[j] = idx < NN ? deg[idx] : 0;
    s += v[j];
  }
  lds[t] = s;
  __syncthreads();
  for (int d = 1; d < 1024; d <<= 1) {
    int x = t >= d ? lds[t - d] : 0;
    __syncthreads();
    lds[t] += x;
    __syncthreads();
  }
  int run = lds[t] - s;
  for (int j = 0; j < 16; ++j) {
    int idx = base + j;
    if (idx < NN) { row_ptr[idx] = run; cursor[idx] = run; run += v[j]; }
  }
  if (t == 1023) row_ptr[NN] = run;
}

__global__ void csr_fill(const int* __restrict__ src, const int* __restrict__ dst,
                         int* __restrict__ cursor, int* __restrict__ cs_e,
                         int* __restrict__ cs_src) {
  int e = blockIdx.x * 256 + threadIdx.x;
  if (e >= NE) return;
  int pos = atomicAdd(&cursor[dst[e]], 1);
  cs_e[pos] = e;
  cs_src[pos] = src[e];
}

// ---- weight transpose + bf16 cast: WT[z*osz + n*256 + k] = bf16(W[k][n]) ----
__global__ void transpose4(const float* __restrict__ W0, const float* __restrict__ W1,
                           const float* __restrict__ W2, const float* __restrict__ W3,
                           int ld, int osz, u16* __restrict__ WT) {
  __shared__ float t[16][17];
  int z = blockIdx.z;
  const float* W = z == 0 ? W0 : (z == 1 ? W1 : (z == 2 ? W2 : W3));
  u16* O = WT + (size_t)z * osz;
  int n0 = blockIdx.x * 16, k0 = blockIdx.y * 16;
  int tx = threadIdx.x, ty = threadIdx.y;
  t[ty][tx] = W[(size_t)(k0 + ty) * ld + n0 + tx];
  __syncthreads();
  O[(size_t)(n0 + ty) * 256 + k0 + tx] = f2bf(t[tx][ty]);
}

// ---------------- bf16 GEMM, 2-phase pipelined: C[M,256] = A[M,256] @ B (B^T given) ----------------
// grid = (M/128, 2, nmat); 128x128 tile, 4 waves; double-buffered LDS, STAGE(next) || compute(cur),
// one barrier per K-step (its implicit vmcnt(0)+lgkmcnt(0) drains the in-flight stage).
__global__ __launch_bounds__(256) void gemm_abt(
    const u16* __restrict__ A,
    const u16* __restrict__ BT0, const u16* __restrict__ BT1, const u16* __restrict__ BT2,
    u16* __restrict__ C0, u16* __restrict__ C1, u16* __restrict__ C2) {
  const int bz = blockIdx.z;
  const u16* BT = bz == 0 ? BT0 : (bz == 1 ? BT1 : BT2);
  u16* C = bz == 0 ? C0 : (bz == 1 ? C1 : C2);
  const int m0 = blockIdx.x * 128;
  const int n0 = blockIdx.y * 128;
  __shared__ u16 lA[2][128 * 64];
  __shared__ u16 lB[2][128 * 64];
  const int tid = threadIdx.x;
  const int lane = tid & 63;
  const int wid = tid >> 6;
  const int wr = (wid >> 1) * 64;
  const int wc = (wid & 1) * 64;
  const int srow = tid >> 3;        // staging: 16B per thread, 8 threads per 64-col row
  const int scol = (tid & 7) * 8;
  f32x4 acc[4][4] = {};
#define STAGE(buf, kb)                                                                         \
  {                                                                                            \
    _Pragma("unroll") for (int i = 0; i < 4; ++i) {                                            \
      const int row = srow + i * 32;                                                           \
      __builtin_amdgcn_global_load_lds(                                                        \
          (const __attribute__((address_space(1))) void*)(A + (size_t)(m0 + row) * 256 + (kb) + scol), \
          (__attribute__((address_space(3))) void*)(lA[buf] + row * 64 + scol), 16, 0, 0);     \
      __builtin_amdgcn_global_load_lds(                                                        \
          (const __attribute__((address_space(1))) void*)(BT + (size_t)(n0 + row) * 256 + (kb) + scol), \
          (__attribute__((address_space(3))) void*)(lB[buf] + row * 64 + scol), 16, 0, 0);     \
    }                                                                                          \
  }
  STAGE(0, 0)
  __syncthreads();
#pragma unroll
  for (int t = 0; t < 4; ++t) {
    if (t < 3) STAGE((t + 1) & 1, (t + 1) * 64)
    const u16* pA = lA[t & 1];
    const u16* pB = lB[t & 1];
#pragma unroll
    for (int kk = 0; kk < 2; ++kk) {
      bf16x8 af[4], bfr[4];
#pragma unroll
      for (int m = 0; m < 4; ++m)
        af[m] = *(const bf16x8*)(pA + (wr + m * 16 + (lane & 15)) * 64 + kk * 32 + (lane >> 4) * 8);
#pragma unroll
      for (int n = 0; n < 4; ++n)
        bfr[n] = *(const bf16x8*)(pB + (wc + n * 16 + (lane & 15)) * 64 + kk * 32 + (lane >> 4) * 8);
#pragma unroll
      for (int m = 0; m < 4; ++m)
#pragma unroll
        for (int n = 0; n < 4; ++n)
          acc[m][n] = __builtin_amdgcn_mfma_f32_16x16x32_bf16(af[m], bfr[n], acc[m][n], 0, 0, 0);
    }
    __syncthreads();   // all reads of buf[t&1] done; in-flight stage of buf[(t+1)&1] drained
  }
#undef STAGE
  const int cr = (lane >> 4) * 4;  // C/D: col = lane&15, row = (lane>>4)*4 + reg
  const int cc = lane & 15;
#pragma unroll
  for (int m = 0; m < 4; ++m)
#pragma unroll
    for (int n = 0; n < 4; ++n) {
      size_t base = (size_t)(m0 + wr + m * 16 + cr) * 256 + (n0 + wc + n * 16 + cc);
#pragma unroll
      for (int j = 0; j < 4; ++j)
        C[base + (size_t)j * 256] = f2bf(acc[m][n][j]);
    }
}

// ---- hidden-layer edge pass: f-state residual in bf16 (in place), logits ----
__global__ __launch_bounds__(256) void edge_hidden(
    const u16* __restrict__ t_ni, const u16* __restrict__ t_nj, const u16* __restrict__ fW,
    const int* __restrict__ src, const int* __restrict__ dst,
    const float* __restrict__ bias, const float* __restrict__ attn,
    u16* __restrict__ f_bf, float* __restrict__ exb) {
  int e = blockIdx.x * 4 + (threadIdx.x >> 6);
  if (e >= NE) return;
  int lane = threadIdx.x & 63;
  int is = src[e], id = dst[e];
  int c = lane * 4;
  u16x4 va = *(const u16x4*)(t_ni + (size_t)is * 256 + c);
  u16x4 vb = *(const u16x4*)(t_nj + (size_t)id * 256 + c);
  u16x4 vc = *(const u16x4*)(fW + (size_t)e * 256 + c);
  f32x4 vbi = *(const f32x4*)(bias + c);
  int h = lane >> 3;
  f32x4 vat = *(const f32x4*)(attn + h * 32 + (lane & 7) * 4);
  size_t idx0 = (size_t)e * 256 + c;
  u16x4 fo = *(u16x4*)(f_bf + idx0);
  float part = 0.f;
#pragma unroll
  for (int j = 0; j < 4; ++j) {
    float y = bf2f(va[j]) + bf2f(vb[j]) + bf2f(vc[j]) + vbi[j];
    y = y > 0.f ? y : 0.01f * y;           // leaky_relu
    part += y * vat[j];                    // attention logit partial
    float el = y > 0.f ? y : expm1f(y);    // elu(f_out)
    fo[j] = f2bf(bf2f(fo[j]) + el);        // residual in bf16
  }
  *(u16x4*)(f_bf + idx0) = fo;
  part += __shfl_xor(part, 1);
  part += __shfl_xor(part, 2);
  part += __shfl_xor(part, 4);             // reduce the 8 lanes of this head
  part = fminf(fmaxf(part, -30.f), 30.f);  // insurance: exp can never overflow
  if ((lane & 7) == 0) exb[(size_t)e * 8 + h] = expf(part);
}

// ---- hidden gather: softmax denom + weighted msg + elu + residual (no atomics) ----
__global__ __launch_bounds__(256) void node_gather_hidden(
    const u16* __restrict__ t_node, const int* __restrict__ row_ptr,
    const int* __restrict__ cs_e, const int* __restrict__ cs_src,
    const float* __restrict__ exb, float* __restrict__ n_cur, u16* __restrict__ n_bf) {
  int node = blockIdx.x * 4 + (threadIdx.x >> 6);
  if (node >= NN) return;
  int lane = threadIdx.x & 63;
  int c = lane * 4, h = lane >> 3;
  int beg = row_ptr[node], end = row_ptr[node + 1];
  float denom = 0.f;
  float acc[4] = {0.f, 0.f, 0.f, 0.f};
  for (int p = beg; p < end; ++p) {
    float a = exb[(size_t)cs_e[p] * 8 + h];
    denom += a;
    u16x4 hv = *(const u16x4*)(t_node + (size_t)cs_src[p] * 256 + c);
#pragma unroll
    for (int j = 0; j < 4; ++j) acc[j] += a * bf2f(hv[j]);
  }
  float inv = denom > 0.f ? 1.f / denom : 0.f;
  size_t i0 = (size_t)node * 256 + c;
  f32x4 nv = *(f32x4*)(n_cur + i0);
  u16x4 bv;
#pragma unroll
  for (int j = 0; j < 4; ++j) {
    float t = acc[j] * inv;
    t = t > 0.f ? t : expm1f(t);   // elu
    nv[j] += t;
    bv[j] = f2bf(nv[j]);
  }
  *(f32x4*)(n_cur + i0) = nv;
  *(u16x4*)(n_bf + i0) = bv;
}

// ---- final-layer edge pass, bf16 head-mean accumulator variant ----
__global__ __launch_bounds__(256) void edge_final_bf(
    const u16* __restrict__ t_ni, const u16* __restrict__ t_nj, const u16* __restrict__ fW,
    const int* __restrict__ src, const int* __restrict__ dst,
    const float* __restrict__ bias, const float* __restrict__ attn,
    u16* __restrict__ facc, float* __restrict__ exb, int first) {
  int e = blockIdx.x * 4 + (threadIdx.x >> 6);
  if (e >= NE) return;
  int lane = threadIdx.x & 63;
  int is = src[e], id = dst[e];
  int c = lane * 4;
  u16x4 va = *(const u16x4*)(t_ni + (size_t)is * 256 + c);
  u16x4 vb = *(const u16x4*)(t_nj + (size_t)id * 256 + c);
  u16x4 vc = *(const u16x4*)(fW + (size_t)e * 256 + c);
  f32x4 vbi = *(const f32x4*)(bias + c);
  f32x4 vat = *(const f32x4*)(attn + c);
  size_t idx0 = (size_t)e * 256 + c;
  float part = 0.f;
  float ys[4];
#pragma unroll
  for (int j = 0; j < 4; ++j) {
    float y = bf2f(va[j]) + bf2f(vb[j]) + bf2f(vc[j]) + vbi[j];
    y = y > 0.f ? y : 0.01f * y;   // leaky_relu; final layer: head-mean, no elu
    part += y * vat[j];
    ys[j] = 0.125f * y;
  }
  u16x4 fo;
  if (first) {
#pragma unroll
    for (int j = 0; j < 4; ++j) fo[j] = f2bf(ys[j]);
  } else {
    fo = *(u16x4*)(facc + idx0);
#pragma unroll
    for (int j = 0; j < 4; ++j) fo[j] = f2bf(bf2f(fo[j]) + ys[j]);
  }
  *(u16x4*)(facc + idx0) = fo;
#pragma unroll
  for (int m = 1; m < 64; m <<= 1) part += __shfl_xor(part, m);
  part = fminf(fmaxf(part, -30.f), 30.f);
  if (lane == 0) exb[e] = expf(part);
}

// ---- final-layer edge pass, f32 accumulator variant (fallback; acc lives in d_out) ----
__global__ __launch_bounds__(256) void edge_final_f32(
    const u16* __restrict__ t_ni, const u16* __restrict__ t_nj, const u16* __restrict__ fW,
    const int* __restrict__ src, const int* __restrict__ dst,
    const float* __restrict__ bias, const float* __restrict__ attn,
    float* __restrict__ facc, float* __restrict__ exb, int first) {
  int e = blockIdx.x * 4 + (threadIdx.x >> 6);
  if (e >= NE) return;
  int lane = threadIdx.x & 63;
  int is = src[e], id = dst[e];
  int c = lane * 4;
  u16x4 va = *(const u16x4*)(t_ni + (size_t)is * 256 + c);
  u16x4 vb = *(const u16x4*)(t_nj + (size_t)id * 256 + c);
  u16x4 vc = *(const u16x4*)(fW + (size_t)e * 256 + c);
  f32x4 vbi = *(const f32x4*)(bias + c);
  f32x4 vat = *(const f32x4*)(attn + c);
  size_t idx0 = (size_t)e * 256 + c;
  float part = 0.f;
  f32x4 fo;
  if (first) {
#pragma unroll
    for (int j = 0; j < 4; ++j) fo[j] = 0.f;
  } else {
    fo = *(f32x4*)(facc + idx0);
  }
#pragma unroll
  for (int j = 0; j < 4; ++j) {
    float y = bf2f(va[j]) + bf2f(vb[j]) + bf2f(vc[j]) + vbi[j];
    y = y > 0.f ? y : 0.01f * y;
    part += y * vat[j];
    fo[j] += 0.125f * y;
  }
  *(f32x4*)(facc + idx0) = fo;
#pragma unroll
  for (int m = 1; m < 64; m <<= 1) part += __shfl_xor(part, m);
  part = fminf(fmaxf(part, -30.f), 30.f);
  if (lane == 0) exb[e] = expf(part);
}

// ---- final gather (one head): h_out += (1/8) * softmax-weighted message sum ----
__global__ __launch_bounds__(256) void node_gather_final(
    const u16* __restrict__ t_node, const int* __restrict__ row_ptr,
    const int* __restrict__ cs_e, const int* __restrict__ cs_src,
    const float* __restrict__ exb, float* __restrict__ h_out) {
  int node = blockIdx.x * 4 + (threadIdx.x >> 6);
  if (node >= NN) return;
  int lane = threadIdx.x & 63;
  int c = lane * 4;
  int beg = row_ptr[node], end = row_ptr[node + 1];
  float denom = 0.f;
  float acc[4] = {0.f, 0.f, 0.f, 0.f};
  for (int p = beg; p < end; ++p) {
    float a = exb[cs_e[p]];
    denom += a;
    u16x4 hv = *(const u16x4*)(t_node + (size_t)cs_src[p] * 256 + c);
#pragma unroll
    for (int j = 0; j < 4; ++j) acc[j] += a * bf2f(hv[j]);
  }
  float inv = denom > 0.f ? 0.125f / denom : 0.f;
  size_t i0 = (size_t)node * 256 + c;
  f32x4 ho = *(f32x4*)(h_out + i0);
#pragma unroll
  for (int j = 0; j < 4; ++j) ho[j] += acc[j] * inv;
  *(f32x4*)(h_out + i0) = ho;
}

// ---------------- out_f = f_state(bf16) + facc(bf16) ----------------
__global__ void combine_f_bf(const u16* __restrict__ f_bf, const u16* __restrict__ facc,
                             float* __restrict__ out_f, int n4) {
  for (int i = blockIdx.x * blockDim.x + threadIdx.x; i < n4; i += gridDim.x * blockDim.x) {
    u16x4 s = ((const u16x4*)f_bf)[i];
    u16x4 a = ((const u16x4*)facc)[i];
    f32x4 o;
#pragma unroll
    for (int j = 0; j < 4; ++j) o[j] = bf2f(s[j]) + bf2f(a[j]);
    ((f32x4*)out_f)[i] = o;
  }
}

// ---------------- out_f = f_state(bf16) + out_f(f32, in place) ----------------
__global__ void combine_f_f32(const u16* __restrict__ f_bf, float* __restrict__ out_f, int n4) {
  for (int i = blockIdx.x * blockDim.x + threadIdx.x; i < n4; i += gridDim.x * blockDim.x) {
    u16x4 s = ((const u16x4*)f_bf)[i];
    f32x4 o = ((f32x4*)out_f)[i];
#pragma unroll
    for (int j = 0; j < 4; ++j) o[j] += bf2f(s[j]);
    ((f32x4*)out_f)[i] = o;
  }
}

// ---------------- out_n = n_cur + h_out (f32) ----------------
__global__ void store_n(const float* __restrict__ n_cur, const float* __restrict__ h_out,
                        float* __restrict__ out, int n4) {
  for (int i = blockIdx.x * blockDim.x + threadIdx.x; i < n4; i += gridDim.x * blockDim.x) {
    f32x4 av = ((const f32x4*)n_cur)[i];
    f32x4 bv = ((const f32x4*)h_out)[i];
#pragma unroll
    for (int j = 0; j < 4; ++j) av[j] += bv[j];
    ((f32x4*)out)[i] = av;
  }
}

extern "C" void kernel_launch(void* const* d_in, const int* in_sizes, int n_in,
                              void* d_out, int out_size, void* d_ws, size_t ws_size,
                              hipStream_t stream) {
  const float* nfeat   = (const float*)d_in[0];
  const float* efeat   = (const float*)d_in[1];
  const int*   src     = (const int*)d_in[2];
  const int*   dst     = (const int*)d_in[3];
  const float* Wnode_h = (const float*)d_in[4];
  const float* Wni_h   = (const float*)d_in[5];
  const float* Wnj_h   = (const float*)d_in[6];
  const float* Wfij_h  = (const float*)d_in[7];
  const float* attn_h  = (const float*)d_in[8];
  const float* bias_h  = (const float*)d_in[9];
  const float* Wnode_l = (const float*)d_in[10];
  const float* Wni_l   = (const float*)d_in[11];
  const float* Wnj_l   = (const float*)d_in[12];
  const float* Wfij_l  = (const float*)d_in[13];
  const float* attn_l  = (const float*)d_in[14];
  const float* bias_l  = (const float*)d_in[15];

  // base workspace ~139 MB; facc (+33 MB) only used if it fits in ws_size
  char* ws = (char*)d_ws;
  size_t off = 0;
  auto alloc = [&](size_t b) { char* p = ws + off; off += (b + 255) & ~(size_t)255; return p; };
  float* n_cur = (float*)alloc((size_t)NN * 256 * 4);   // node state (f32)
  u16* n_bf    = (u16*)alloc((size_t)NN * 256 * 2);     // bf16 mirror (GEMM A)
  u16* f_bf    = (u16*)alloc((size_t)NE * 256 * 2);     // edge state (bf16 only)
  u16* t_ni    = (u16*)alloc((size_t)NN * 256 * 2);     // GEMM outputs (bf16)
  u16* t_nj    = (u16*)alloc((size_t)NN * 256 * 2);
  u16* t_node  = (u16*)alloc((size_t)NN * 256 * 2);
  u16* fW      = (u16*)alloc((size_t)NE * 256 * 2);
  float* exb   = (float*)alloc((size_t)NE * 8 * 4);     // exp(logits)
  float* h_out = (float*)alloc((size_t)NN * 256 * 4);   // final node accumulator (f32)
  u16* WT      = (u16*)alloc((size_t)4 * 65536 * 2);    // hidden-layer transposed weights
  u16* WTF     = (u16*)alloc((size_t)4 * 524288 * 2);   // final-layer transposed weights (all heads)
  int* deg     = (int*)alloc((size_t)NN * 4);           // CSR
  int* cursor  = (int*)alloc((size_t)NN * 4);
  int* row_ptr = (int*)alloc((size_t)(NN + 1) * 4);
  int* cs_e    = (int*)alloc((size_t)NE * 4);
  int* cs_src  = (int*)alloc((size_t)NE * 4);
  u16* facc    = (u16*)alloc((size_t)NE * 256 * 2);     // bf16 head-mean accumulator (optional)
  const bool bfacc = (off <= ws_size);

  u16* WT_node = WT;
  u16* WT_ni   = WT + 65536;
  u16* WT_nj   = WT + 2 * 65536;
  u16* WT_fij  = WT + 3 * 65536;

  float* out_n = (float*)d_out;
  float* out_f = out_n + (size_t)NN * 256;

  // CSR build (reused by all 10 message passes)
  hipMemsetAsync(deg, 0, (size_t)NN * 4, stream);
  deg_hist<<<(NE + 255) / 256, 256, 0, stream>>>(dst, deg);
  scan_deg<<<1, 1024, 0, stream>>>(deg, row_ptr, cursor);
  csr_fill<<<(NE + 255) / 256, 256, 0, stream>>>(src, dst, cursor, cs_e, cs_src);

  cast_init<<<1024, 256, 0, stream>>>(nfeat, n_cur, n_bf, NN * 256 / 4);
  cast_bf<<<2048, 256, 0, stream>>>(efeat, f_bf, NE * 256 / 4);

  for (int l = 0; l < 2; ++l) {
    transpose4<<<dim3(16, 16, 4), dim3(16, 16), 0, stream>>>(
        Wnode_h + (size_t)l * 65536, Wni_h + (size_t)l * 65536,
        Wnj_h + (size_t)l * 65536, Wfij_h + (size_t)l * 65536, 256, 65536, WT);
    gemm_abt<<<dim3(125, 2, 3), 256, 0, stream>>>(n_bf, WT_ni, WT_nj, WT_node, t_ni, t_nj, t_node);
    gemm_abt<<<dim3(500, 2, 1), 256, 0, stream>>>(f_bf, WT_fij, WT_fij, WT_fij, fW, fW, fW);
    edge_hidden<<<16000, 256, 0, stream>>>(t_ni, t_nj, fW, src, dst,
        bias_h + (size_t)l * 256, attn_h + (size_t)l * 256, f_bf, exb);
    node_gather_hidden<<<4000, 256, 0, stream>>>(t_node, row_ptr, cs_e, cs_src, exb, n_cur, n_bf);
  }

  // final layer: transpose all heads' weights once, then per-head GEMM + edge + gather
  transpose4<<<dim3(128, 16, 4), dim3(16, 16), 0, stream>>>(
      Wnode_l, Wni_l, Wnj_l, Wfij_l, 2048, 524288, WTF);
  hipMemsetAsync(h_out, 0, (size_t)NN * 256 * 4, stream);
  for (int h = 0; h < 8; ++h) {
    const u16* Bn = WTF + (size_t)0 * 524288 + (size_t)h * 65536;   // Wnode_l head slice
    const u16* Bi = WTF + (size_t)1 * 524288 + (size_t)h * 65536;   // Wni_l
    const u16* Bj = WTF + (size_t)2 * 524288 + (size_t)h * 65536;   // Wnj_l
    const u16* Bf = WTF + (size_t)3 * 524288 + (size_t)h * 65536;   // Wfij_l
    gemm_abt<<<dim3(125, 2, 3), 256, 0, stream>>>(n_bf, Bi, Bj, Bn, t_ni, t_nj, t_node);
    gemm_abt<<<dim3(500, 2, 1), 256, 0, stream>>>(f_bf, Bf, Bf, Bf, fW, fW, fW);
    if (bfacc)
      edge_final_bf<<<16000, 256, 0, stream>>>(t_ni, t_nj, fW, src, dst,
          bias_l + (size_t)h * 256, attn_l + (size_t)h * 256, facc, exb, h == 0);
    else
      edge_final_f32<<<16000, 256, 0, stream>>>(t_ni, t_nj, fW, src, dst,
          bias_l + (size_t)h * 256, attn_l + (size_t)h * 256, out_f, exb, h == 0);
    node_gather_final<<<4000, 256, 0, stream>>>(t_node, row_ptr, cs_e, cs_src, exb, h_out);
  }

  if (bfacc)
    combine_f_bf<<<2048, 256, 0, stream>>>(f_bf, facc, out_f, NE * 256 / 4);
  else
    combine_f_f32<<<2048, 256, 0, stream>>>(f_bf, out_f, NE * 256 / 4);
  store_n<<<1024, 256, 0, stream>>>(n_cur, h_out, out_n, NN * 256 / 4);
}

// Round 6
// 802.694 us; speedup vs baseline: 3.6637x; 1.1236x over previous
//
#include <hip/hip_runtime.h>

typedef unsigned short u16;
typedef __attribute__((ext_vector_type(4))) unsigned short u16x4;
typedef __attribute__((ext_vector_type(4))) float f32x4;
typedef __attribute__((ext_vector_type(8))) __bf16 bf16x8;

#define NN 16000
#define NE 64000
#define ECH 6400   // final-layer edge chunk (10 chunks; 6400/128 = 50 GEMM row-blocks)

__device__ __forceinline__ float bf2f(u16 b) {
  union { unsigned int u; float f; } v; v.u = ((unsigned int)b) << 16; return v.f;
}
__device__ __forceinline__ u16 f2bf(float x) {
  union { float f; unsigned int u; } v; v.f = x;
  unsigned int r = v.u + 0x7FFFu + ((v.u >> 16) & 1u);
  return (u16)(r >> 16);
}

// ---------------- node init: f32 working copy + bf16 mirror ----------------
__global__ void cast_init(const float* __restrict__ in, float* __restrict__ outf,
                          u16* __restrict__ outb, int n4) {
  for (int i = blockIdx.x * blockDim.x + threadIdx.x; i < n4; i += gridDim.x * blockDim.x) {
    f32x4 v = ((const f32x4*)in)[i];
    u16x4 b;
#pragma unroll
    for (int j = 0; j < 4; ++j) b[j] = f2bf(v[j]);
    ((f32x4*)outf)[i] = v;
    ((u16x4*)outb)[i] = b;
  }
}

// ---------------- edge init: bf16 state only ----------------
__global__ void cast_bf(const float* __restrict__ in, u16* __restrict__ outb, int n4) {
  for (int i = blockIdx.x * blockDim.x + threadIdx.x; i < n4; i += gridDim.x * blockDim.x) {
    f32x4 v = ((const f32x4*)in)[i];
    u16x4 b;
#pragma unroll
    for (int j = 0; j < 4; ++j) b[j] = f2bf(v[j]);
    ((u16x4*)outb)[i] = b;
  }
}

// ---------------- CSR build ----------------
__global__ void deg_hist(const int* __restrict__ dst, int* __restrict__ deg) {
  int e = blockIdx.x * 256 + threadIdx.x;
  if (e < NE) atomicAdd(&deg[dst[e]], 1);
}

__global__ __launch_bounds__(1024) void scan_deg(const int* __restrict__ deg,
                                                 int* __restrict__ row_ptr,
                                                 int* __restrict__ cursor) {
  __shared__ int lds[1024];
  int t = threadIdx.x;
  int base = t * 16;
  int v[16];
  int s = 0;
#pragma unroll
  for (int j = 0; j < 16; ++j) {
    int idx = base + j;
    v[j] = idx < NN ? deg[idx] : 0;
    s += v[j];
  }
  lds[t] = s;
  __syncthreads();
  for (int d = 1; d < 1024; d <<= 1) {
    int x = t >= d ? lds[t - d] : 0;
    __syncthreads();
    lds[t] += x;
    __syncthreads();
  }
  int run = lds[t] - s;
  for (int j = 0; j < 16; ++j) {
    int idx = base + j;
    if (idx < NN) { row_ptr[idx] = run; cursor[idx] = run; run += v[j]; }
  }
  if (t == 1023) row_ptr[NN] = run;
}

__global__ void csr_fill(const int* __restrict__ src, const int* __restrict__ dst,
                         int* __restrict__ cursor, int* __restrict__ cs_e,
                         int* __restrict__ cs_src) {
  int e = blockIdx.x * 256 + threadIdx.x;
  if (e >= NE) return;
  int pos = atomicAdd(&cursor[dst[e]], 1);
  cs_e[pos] = e;
  cs_src[pos] = src[e];
}

// ---- weight transpose + bf16 cast: WT[z*osz + n*256 + k] = bf16(W[k][n]) ----
__global__ void transpose4(const float* __restrict__ W0, const float* __restrict__ W1,
                           const float* __restrict__ W2, const float* __restrict__ W3,
                           int ld, int osz, u16* __restrict__ WT) {
  __shared__ float t[16][17];
  int z = blockIdx.z;
  const float* W = z == 0 ? W0 : (z == 1 ? W1 : (z == 2 ? W2 : W3));
  u16* O = WT + (size_t)z * osz;
  int n0 = blockIdx.x * 16, k0 = blockIdx.y * 16;
  int tx = threadIdx.x, ty = threadIdx.y;
  t[ty][tx] = W[(size_t)(k0 + ty) * ld + n0 + tx];
  __syncthreads();
  O[(size_t)(n0 + ty) * 256 + k0 + tx] = f2bf(t[tx][ty]);
}

// ------------- bf16 GEMM, 2-phase pipelined: C[M,ldc] = A[M,256] @ B (B^T given) -------------
// grid = (M/128, ldc/128, nmat); 128x128 tile, 4 waves, double-buffered LDS,
// STAGE(next) || MFMA(cur), one barrier per K-step.
__global__ __launch_bounds__(256) void gemm_abt(
    const u16* __restrict__ A,
    const u16* __restrict__ BT0, const u16* __restrict__ BT1, const u16* __restrict__ BT2,
    u16* __restrict__ C0, u16* __restrict__ C1, u16* __restrict__ C2, int ldc) {
  const int bz = blockIdx.z;
  const u16* BT = bz == 0 ? BT0 : (bz == 1 ? BT1 : BT2);
  u16* C = bz == 0 ? C0 : (bz == 1 ? C1 : C2);
  const int m0 = blockIdx.x * 128;
  const int n0 = blockIdx.y * 128;
  __shared__ u16 lA[2][128 * 64];
  __shared__ u16 lB[2][128 * 64];
  const int tid = threadIdx.x;
  const int lane = tid & 63;
  const int wid = tid >> 6;
  const int wr = (wid >> 1) * 64;
  const int wc = (wid & 1) * 64;
  const int srow = tid >> 3;
  const int scol = (tid & 7) * 8;
  f32x4 acc[4][4] = {};
#define STAGE(buf, kb)                                                                         \
  {                                                                                            \
    _Pragma("unroll") for (int i = 0; i < 4; ++i) {                                            \
      const int row = srow + i * 32;                                                           \
      __builtin_amdgcn_global_load_lds(                                                        \
          (const __attribute__((address_space(1))) void*)(A + (size_t)(m0 + row) * 256 + (kb) + scol), \
          (__attribute__((address_space(3))) void*)(lA[buf] + row * 64 + scol), 16, 0, 0);     \
      __builtin_amdgcn_global_load_lds(                                                        \
          (const __attribute__((address_space(1))) void*)(BT + (size_t)(n0 + row) * 256 + (kb) + scol), \
          (__attribute__((address_space(3))) void*)(lB[buf] + row * 64 + scol), 16, 0, 0);     \
    }                                                                                          \
  }
  STAGE(0, 0)
  __syncthreads();
#pragma unroll
  for (int t = 0; t < 4; ++t) {
    if (t < 3) STAGE((t + 1) & 1, (t + 1) * 64)
    const u16* pA = lA[t & 1];
    const u16* pB = lB[t & 1];
#pragma unroll
    for (int kk = 0; kk < 2; ++kk) {
      bf16x8 af[4], bfr[4];
#pragma unroll
      for (int m = 0; m < 4; ++m)
        af[m] = *(const bf16x8*)(pA + (wr + m * 16 + (lane & 15)) * 64 + kk * 32 + (lane >> 4) * 8);
#pragma unroll
      for (int n = 0; n < 4; ++n)
        bfr[n] = *(const bf16x8*)(pB + (wc + n * 16 + (lane & 15)) * 64 + kk * 32 + (lane >> 4) * 8);
#pragma unroll
      for (int m = 0; m < 4; ++m)
#pragma unroll
        for (int n = 0; n < 4; ++n)
          acc[m][n] = __builtin_amdgcn_mfma_f32_16x16x32_bf16(af[m], bfr[n], acc[m][n], 0, 0, 0);
    }
    __syncthreads();
  }
#undef STAGE
  const int cr = (lane >> 4) * 4;  // C/D: col = lane&15, row = (lane>>4)*4 + reg
  const int cc = lane & 15;
#pragma unroll
  for (int m = 0; m < 4; ++m)
#pragma unroll
    for (int n = 0; n < 4; ++n) {
      size_t base = (size_t)(m0 + wr + m * 16 + cr) * ldc + (n0 + wc + n * 16 + cc);
#pragma unroll
      for (int j = 0; j < 4; ++j)
        C[base + (size_t)j * ldc] = f2bf(acc[m][n][j]);
    }
}

// ---- hidden-layer edge pass: f-state residual in bf16 (in place), logits ----
__global__ __launch_bounds__(256) void edge_hidden(
    const u16* __restrict__ t_ni, const u16* __restrict__ t_nj, const u16* __restrict__ fW,
    const int* __restrict__ src, const int* __restrict__ dst,
    const float* __restrict__ bias, const float* __restrict__ attn,
    u16* __restrict__ f_bf, float* __restrict__ exb) {
  int e = blockIdx.x * 4 + (threadIdx.x >> 6);
  if (e >= NE) return;
  int lane = threadIdx.x & 63;
  int is = src[e], id = dst[e];
  int c = lane * 4;
  u16x4 va = *(const u16x4*)(t_ni + (size_t)is * 256 + c);
  u16x4 vb = *(const u16x4*)(t_nj + (size_t)id * 256 + c);
  u16x4 vc = *(const u16x4*)(fW + (size_t)e * 256 + c);
  f32x4 vbi = *(const f32x4*)(bias + c);
  int h = lane >> 3;
  f32x4 vat = *(const f32x4*)(attn + h * 32 + (lane & 7) * 4);
  size_t idx0 = (size_t)e * 256 + c;
  u16x4 fo = *(u16x4*)(f_bf + idx0);
  float part = 0.f;
#pragma unroll
  for (int j = 0; j < 4; ++j) {
    float y = bf2f(va[j]) + bf2f(vb[j]) + bf2f(vc[j]) + vbi[j];
    y = y > 0.f ? y : 0.01f * y;           // leaky_relu
    part += y * vat[j];                    // attention logit partial
    float el = y > 0.f ? y : expm1f(y);    // elu(f_out)
    fo[j] = f2bf(bf2f(fo[j]) + el);        // residual in bf16
  }
  *(u16x4*)(f_bf + idx0) = fo;
  part += __shfl_xor(part, 1);
  part += __shfl_xor(part, 2);
  part += __shfl_xor(part, 4);             // reduce the 8 lanes of this head
  part = fminf(fmaxf(part, -30.f), 30.f);  // insurance: exp can never overflow
  if ((lane & 7) == 0) exb[(size_t)e * 8 + h] = expf(part);
}

// ---- hidden gather: softmax denom + weighted msg + elu + residual (no atomics) ----
__global__ __launch_bounds__(256) void node_gather_hidden(
    const u16* __restrict__ t_node, const int* __restrict__ row_ptr,
    const int* __restrict__ cs_e, const int* __restrict__ cs_src,
    const float* __restrict__ exb, float* __restrict__ n_cur, u16* __restrict__ n_bf) {
  int node = blockIdx.x * 4 + (threadIdx.x >> 6);
  if (node >= NN) return;
  int lane = threadIdx.x & 63;
  int c = lane * 4, h = lane >> 3;
  int beg = row_ptr[node], end = row_ptr[node + 1];
  float denom = 0.f;
  float acc[4] = {0.f, 0.f, 0.f, 0.f};
  for (int p = beg; p < end; ++p) {
    float a = exb[(size_t)cs_e[p] * 8 + h];
    denom += a;
    u16x4 hv = *(const u16x4*)(t_node + (size_t)cs_src[p] * 256 + c);
#pragma unroll
    for (int j = 0; j < 4; ++j) acc[j] += a * bf2f(hv[j]);
  }
  float inv = denom > 0.f ? 1.f / denom : 0.f;
  size_t i0 = (size_t)node * 256 + c;
  f32x4 nv = *(f32x4*)(n_cur + i0);
  u16x4 bv;
#pragma unroll
  for (int j = 0; j < 4; ++j) {
    float t = acc[j] * inv;
    t = t > 0.f ? t : expm1f(t);   // elu
    nv[j] += t;
    bv[j] = f2bf(nv[j]);
  }
  *(f32x4*)(n_cur + i0) = nv;
  *(u16x4*)(n_bf + i0) = bv;
}

// ---- final-layer edge pass, ALL 8 heads: out_f = f_state + mean_h(y), exb per head ----
// tables t_ni/t_nj are [NN,2048]; fWc is the chunk's [ECH,2048]; one write, no RMW.
__global__ __launch_bounds__(256) void edge_final_all(
    int e0, const u16* __restrict__ t_ni, const u16* __restrict__ t_nj,
    const u16* __restrict__ fWc, const int* __restrict__ src, const int* __restrict__ dst,
    const float* __restrict__ bias, const float* __restrict__ attn,
    const u16* __restrict__ f_bf, float* __restrict__ out_f, float* __restrict__ exb) {
  int ec = blockIdx.x * 4 + (threadIdx.x >> 6);
  if (ec >= ECH) return;
  int e = e0 + ec;
  int lane = threadIdx.x & 63;
  int is = src[e], id = dst[e];
  int c = lane * 4;
  float total[4] = {0.f, 0.f, 0.f, 0.f};
#pragma unroll
  for (int h = 0; h < 8; ++h) {
    u16x4 va = *(const u16x4*)(t_ni + (size_t)is * 2048 + h * 256 + c);
    u16x4 vb = *(const u16x4*)(t_nj + (size_t)id * 2048 + h * 256 + c);
    u16x4 vc = *(const u16x4*)(fWc + (size_t)ec * 2048 + h * 256 + c);
    f32x4 vbi = *(const f32x4*)(bias + h * 256 + c);
    f32x4 vat = *(const f32x4*)(attn + h * 256 + c);
    float part = 0.f;
#pragma unroll
    for (int j = 0; j < 4; ++j) {
      float y = bf2f(va[j]) + bf2f(vb[j]) + bf2f(vc[j]) + vbi[j];
      y = y > 0.f ? y : 0.01f * y;   // leaky_relu; final: head-mean, no elu
      part += y * vat[j];
      total[j] += 0.125f * y;
    }
#pragma unroll
    for (int m = 1; m < 64; m <<= 1) part += __shfl_xor(part, m);
    part = fminf(fmaxf(part, -30.f), 30.f);
    if (lane == 0) exb[(size_t)e * 8 + h] = expf(part);
  }
  size_t i0 = (size_t)e * 256 + c;
  u16x4 fs = *(const u16x4*)(f_bf + i0);
  f32x4 o;
#pragma unroll
  for (int j = 0; j < 4; ++j) o[j] = bf2f(fs[j]) + total[j];
  *(f32x4*)(out_f + i0) = o;
}

// ---- final gather, ALL 8 heads: out_n = n_cur + mean_h(softmax-weighted msg) ----
__global__ __launch_bounds__(256) void node_gather_final_all(
    const u16* __restrict__ t_node, const int* __restrict__ row_ptr,
    const int* __restrict__ cs_e, const int* __restrict__ cs_src,
    const float* __restrict__ exb, const float* __restrict__ n_cur,
    float* __restrict__ out_n) {
  int node = blockIdx.x * 4 + (threadIdx.x >> 6);
  if (node >= NN) return;
  int lane = threadIdx.x & 63;
  int c = lane * 4;
  int beg = row_ptr[node], end = row_ptr[node + 1];
  float total[4] = {0.f, 0.f, 0.f, 0.f};
#pragma unroll 1
  for (int h = 0; h < 8; ++h) {
    float denom = 0.f;
    float macc[4] = {0.f, 0.f, 0.f, 0.f};
    for (int p = beg; p < end; ++p) {
      float a = exb[(size_t)cs_e[p] * 8 + h];
      denom += a;
      u16x4 hv = *(const u16x4*)(t_node + (size_t)cs_src[p] * 2048 + h * 256 + c);
#pragma unroll
      for (int j = 0; j < 4; ++j) macc[j] += a * bf2f(hv[j]);
    }
    float inv = denom > 0.f ? 0.125f / denom : 0.f;
#pragma unroll
    for (int j = 0; j < 4; ++j) total[j] += macc[j] * inv;
  }
  size_t i0 = (size_t)node * 256 + c;
  f32x4 nv = *(const f32x4*)(n_cur + i0);
#pragma unroll
  for (int j = 0; j < 4; ++j) nv[j] += total[j];
  *(f32x4*)(out_n + i0) = nv;
}

extern "C" void kernel_launch(void* const* d_in, const int* in_sizes, int n_in,
                              void* d_out, int out_size, void* d_ws, size_t ws_size,
                              hipStream_t stream) {
  const float* nfeat   = (const float*)d_in[0];
  const float* efeat   = (const float*)d_in[1];
  const int*   src     = (const int*)d_in[2];
  const int*   dst     = (const int*)d_in[3];
  const float* Wnode_h = (const float*)d_in[4];
  const float* Wni_h   = (const float*)d_in[5];
  const float* Wnj_h   = (const float*)d_in[6];
  const float* Wfij_h  = (const float*)d_in[7];
  const float* attn_h  = (const float*)d_in[8];
  const float* bias_h  = (const float*)d_in[9];
  const float* Wnode_l = (const float*)d_in[10];
  const float* Wni_l   = (const float*)d_in[11];
  const float* Wnj_l   = (const float*)d_in[12];
  const float* Wfij_l  = (const float*)d_in[13];
  const float* attn_l  = (const float*)d_in[14];
  const float* bias_l  = (const float*)d_in[15];

  // workspace ~262 MB (ws_size ≈ 327 MB per harness poison-fill evidence)
  char* ws = (char*)d_ws;
  size_t off = 0;
  auto alloc = [&](size_t b) { char* p = ws + off; off += (b + 255) & ~(size_t)255; return p; };
  float* n_cur = (float*)alloc((size_t)NN * 256 * 4);     // node state (f32)
  u16* n_bf    = (u16*)alloc((size_t)NN * 256 * 2);       // bf16 mirror (GEMM A)
  u16* f_bf    = (u16*)alloc((size_t)NE * 256 * 2);       // edge state (bf16)
  u16* t_ni    = (u16*)alloc((size_t)NN * 2048 * 2);      // final-layer node tables [NN,2048]
  u16* t_nj    = (u16*)alloc((size_t)NN * 2048 * 2);
  u16* t_node  = (u16*)alloc((size_t)NN * 2048 * 2);
  u16* fW      = (u16*)alloc((size_t)NE * 256 * 2);       // hidden fW [NE,256]; final chunk [ECH,2048] aliases
  float* exb   = (float*)alloc((size_t)NE * 8 * 4);       // exp(logits)
  u16* WT      = (u16*)alloc((size_t)4 * 65536 * 2);      // hidden transposed weights
  u16* WTF     = (u16*)alloc((size_t)4 * 524288 * 2);     // final transposed weights
  int* deg     = (int*)alloc((size_t)NN * 4);             // CSR
  int* cursor  = (int*)alloc((size_t)NN * 4);
  int* row_ptr = (int*)alloc((size_t)(NN + 1) * 4);
  int* cs_e    = (int*)alloc((size_t)NE * 4);
  int* cs_src  = (int*)alloc((size_t)NE * 4);

  u16* WT_node = WT;
  u16* WT_ni   = WT + 65536;
  u16* WT_nj   = WT + 2 * 65536;
  u16* WT_fij  = WT + 3 * 65536;
  u16* WTF_node = WTF;
  u16* WTF_ni   = WTF + (size_t)1 * 524288;
  u16* WTF_nj   = WTF + (size_t)2 * 524288;
  u16* WTF_fij  = WTF + (size_t)3 * 524288;

  float* out_n = (float*)d_out;
  float* out_f = out_n + (size_t)NN * 256;

  // CSR build (reused by all message passes)
  hipMemsetAsync(deg, 0, (size_t)NN * 4, stream);
  deg_hist<<<(NE + 255) / 256, 256, 0, stream>>>(dst, deg);
  scan_deg<<<1, 1024, 0, stream>>>(deg, row_ptr, cursor);
  csr_fill<<<(NE + 255) / 256, 256, 0, stream>>>(src, dst, cursor, cs_e, cs_src);

  cast_init<<<1024, 256, 0, stream>>>(nfeat, n_cur, n_bf, NN * 256 / 4);
  cast_bf<<<2048, 256, 0, stream>>>(efeat, f_bf, NE * 256 / 4);

  // hidden layers (t_ni/t_nj/t_node used as [NN,256] tables here)
  for (int l = 0; l < 2; ++l) {
    transpose4<<<dim3(16, 16, 4), dim3(16, 16), 0, stream>>>(
        Wnode_h + (size_t)l * 65536, Wni_h + (size_t)l * 65536,
        Wnj_h + (size_t)l * 65536, Wfij_h + (size_t)l * 65536, 256, 65536, WT);
    gemm_abt<<<dim3(125, 2, 3), 256, 0, stream>>>(n_bf, WT_ni, WT_nj, WT_node,
                                                  t_ni, t_nj, t_node, 256);
    gemm_abt<<<dim3(500, 2, 1), 256, 0, stream>>>(f_bf, WT_fij, WT_fij, WT_fij,
                                                  fW, fW, fW, 256);
    edge_hidden<<<16000, 256, 0, stream>>>(t_ni, t_nj, fW, src, dst,
        bias_h + (size_t)l * 256, attn_h + (size_t)l * 256, f_bf, exb);
    node_gather_hidden<<<4000, 256, 0, stream>>>(t_node, row_ptr, cs_e, cs_src, exb, n_cur, n_bf);
  }

  // final layer: full-width node tables once, then edge-chunked f-GEMM + all-heads edge pass
  transpose4<<<dim3(128, 16, 4), dim3(16, 16), 0, stream>>>(
      Wnode_l, Wni_l, Wnj_l, Wfij_l, 2048, 524288, WTF);
  gemm_abt<<<dim3(125, 16, 3), 256, 0, stream>>>(n_bf, WTF_ni, WTF_nj, WTF_node,
                                                 t_ni, t_nj, t_node, 2048);
  for (int cchunk = 0; cchunk < NE / ECH; ++cchunk) {
    const u16* Ac = f_bf + (size_t)cchunk * ECH * 256;
    gemm_abt<<<dim3(ECH / 128, 16, 1), 256, 0, stream>>>(Ac, WTF_fij, WTF_fij, WTF_fij,
                                                         fW, fW, fW, 2048);
    edge_final_all<<<ECH / 4, 256, 0, stream>>>(cchunk * ECH, t_ni, t_nj, fW, src, dst,
                                                bias_l, attn_l, f_bf, out_f, exb);
  }
  node_gather_final_all<<<4000, 256, 0, stream>>>(t_node, row_ptr, cs_e, cs_src,
                                                  exb, n_cur, out_n);
}

// Round 7
// 764.160 us; speedup vs baseline: 3.8484x; 1.0504x over previous
//
#include <hip/hip_runtime.h>

typedef unsigned short u16;
typedef __attribute__((ext_vector_type(4))) unsigned short u16x4;
typedef __attribute__((ext_vector_type(4))) float f32x4;
typedef __attribute__((ext_vector_type(8))) __bf16 bf16x8;

#define NN 16000
#define NE 64000
#define ECH 6400   // final-layer edge chunk (10 chunks)

__device__ __forceinline__ float bf2f(u16 b) {
  union { unsigned int u; float f; } v; v.u = ((unsigned int)b) << 16; return v.f;
}
__device__ __forceinline__ u16 f2bf(float x) {
  union { float f; unsigned int u; } v; v.f = x;
  unsigned int r = v.u + 0x7FFFu + ((v.u >> 16) & 1u);
  return (u16)(r >> 16);
}

// ---------------- node init: f32 working copy + bf16 mirror ----------------
__global__ void cast_init(const float* __restrict__ in, float* __restrict__ outf,
                          u16* __restrict__ outb, int n4) {
  for (int i = blockIdx.x * blockDim.x + threadIdx.x; i < n4; i += gridDim.x * blockDim.x) {
    f32x4 v = ((const f32x4*)in)[i];
    u16x4 b;
#pragma unroll
    for (int j = 0; j < 4; ++j) b[j] = f2bf(v[j]);
    ((f32x4*)outf)[i] = v;
    ((u16x4*)outb)[i] = b;
  }
}

// ---------------- edge init: bf16 state only ----------------
__global__ void cast_bf(const float* __restrict__ in, u16* __restrict__ outb, int n4) {
  for (int i = blockIdx.x * blockDim.x + threadIdx.x; i < n4; i += gridDim.x * blockDim.x) {
    f32x4 v = ((const f32x4*)in)[i];
    u16x4 b;
#pragma unroll
    for (int j = 0; j < 4; ++j) b[j] = f2bf(v[j]);
    ((u16x4*)outb)[i] = b;
  }
}

// ---------------- CSR build ----------------
__global__ void deg_hist(const int* __restrict__ dst, int* __restrict__ deg) {
  int e = blockIdx.x * 256 + threadIdx.x;
  if (e < NE) atomicAdd(&deg[dst[e]], 1);
}

__global__ __launch_bounds__(1024) void scan_deg(const int* __restrict__ deg,
                                                 int* __restrict__ row_ptr,
                                                 int* __restrict__ cursor) {
  __shared__ int lds[1024];
  int t = threadIdx.x;
  int base = t * 16;
  int v[16];
  int s = 0;
#pragma unroll
  for (int j = 0; j < 16; ++j) {
    int idx = base + j;
    v[j] = idx < NN ? deg[idx] : 0;
    s += v[j];
  }
  lds[t] = s;
  __syncthreads();
  for (int d = 1; d < 1024; d <<= 1) {
    int x = t >= d ? lds[t - d] : 0;
    __syncthreads();
    lds[t] += x;
    __syncthreads();
  }
  int run = lds[t] - s;
  for (int j = 0; j < 16; ++j) {
    int idx = base + j;
    if (idx < NN) { row_ptr[idx] = run; cursor[idx] = run; run += v[j]; }
  }
  if (t == 1023) row_ptr[NN] = run;
}

__global__ void csr_fill(const int* __restrict__ src, const int* __restrict__ dst,
                         int* __restrict__ cursor, int* __restrict__ cs_e,
                         int* __restrict__ cs_src) {
  int e = blockIdx.x * 256 + threadIdx.x;
  if (e >= NE) return;
  int pos = atomicAdd(&cursor[dst[e]], 1);
  cs_e[pos] = e;
  cs_src[pos] = src[e];
}

// ---- weight transpose + bf16 cast: WT[z*osz + n*256 + k] = bf16(W[k][n]) ----
__global__ void transpose4(const float* __restrict__ W0, const float* __restrict__ W1,
                           const float* __restrict__ W2, const float* __restrict__ W3,
                           int ld, int osz, u16* __restrict__ WT) {
  __shared__ float t[16][17];
  int z = blockIdx.z;
  const float* W = z == 0 ? W0 : (z == 1 ? W1 : (z == 2 ? W2 : W3));
  u16* O = WT + (size_t)z * osz;
  int n0 = blockIdx.x * 16, k0 = blockIdx.y * 16;
  int tx = threadIdx.x, ty = threadIdx.y;
  t[ty][tx] = W[(size_t)(k0 + ty) * ld + n0 + tx];
  __syncthreads();
  O[(size_t)(n0 + ty) * 256 + k0 + tx] = f2bf(t[tx][ty]);
}

// ------------- bf16 GEMM, 2-phase pipelined: C[M,ldc] = A[M,256] @ B (B^T given) -------------
// grid = (ldc/128, M/128, nmat) — N-dim FASTEST: 16 consecutive blocks share one A-tile,
// stream B (<=1MB, L2-resident) => A fetched ~once instead of N/128 times.
__global__ __launch_bounds__(256) void gemm_abt(
    const u16* __restrict__ A,
    const u16* __restrict__ BT0, const u16* __restrict__ BT1, const u16* __restrict__ BT2,
    u16* __restrict__ C0, u16* __restrict__ C1, u16* __restrict__ C2, int ldc) {
  const int bz = blockIdx.z;
  const u16* BT = bz == 0 ? BT0 : (bz == 1 ? BT1 : BT2);
  u16* C = bz == 0 ? C0 : (bz == 1 ? C1 : C2);
  const int m0 = blockIdx.y * 128;
  const int n0 = blockIdx.x * 128;
  __shared__ u16 lA[2][128 * 64];
  __shared__ u16 lB[2][128 * 64];
  const int tid = threadIdx.x;
  const int lane = tid & 63;
  const int wid = tid >> 6;
  const int wr = (wid >> 1) * 64;
  const int wc = (wid & 1) * 64;
  const int srow = tid >> 3;
  const int scol = (tid & 7) * 8;
  f32x4 acc[4][4] = {};
#define STAGE(buf, kb)                                                                         \
  {                                                                                            \
    _Pragma("unroll") for (int i = 0; i < 4; ++i) {                                            \
      const int row = srow + i * 32;                                                           \
      __builtin_amdgcn_global_load_lds(                                                        \
          (const __attribute__((address_space(1))) void*)(A + (size_t)(m0 + row) * 256 + (kb) + scol), \
          (__attribute__((address_space(3))) void*)(lA[buf] + row * 64 + scol), 16, 0, 0);     \
      __builtin_amdgcn_global_load_lds(                                                        \
          (const __attribute__((address_space(1))) void*)(BT + (size_t)(n0 + row) * 256 + (kb) + scol), \
          (__attribute__((address_space(3))) void*)(lB[buf] + row * 64 + scol), 16, 0, 0);     \
    }                                                                                          \
  }
  STAGE(0, 0)
  __syncthreads();
#pragma unroll
  for (int t = 0; t < 4; ++t) {
    if (t < 3) STAGE((t + 1) & 1, (t + 1) * 64)
    const u16* pA = lA[t & 1];
    const u16* pB = lB[t & 1];
#pragma unroll
    for (int kk = 0; kk < 2; ++kk) {
      bf16x8 af[4], bfr[4];
#pragma unroll
      for (int m = 0; m < 4; ++m)
        af[m] = *(const bf16x8*)(pA + (wr + m * 16 + (lane & 15)) * 64 + kk * 32 + (lane >> 4) * 8);
#pragma unroll
      for (int n = 0; n < 4; ++n)
        bfr[n] = *(const bf16x8*)(pB + (wc + n * 16 + (lane & 15)) * 64 + kk * 32 + (lane >> 4) * 8);
#pragma unroll
      for (int m = 0; m < 4; ++m)
#pragma unroll
        for (int n = 0; n < 4; ++n)
          acc[m][n] = __builtin_amdgcn_mfma_f32_16x16x32_bf16(af[m], bfr[n], acc[m][n], 0, 0, 0);
    }
    __syncthreads();
  }
#undef STAGE
  const int cr = (lane >> 4) * 4;  // C/D: col = lane&15, row = (lane>>4)*4 + reg
  const int cc = lane & 15;
#pragma unroll
  for (int m = 0; m < 4; ++m)
#pragma unroll
    for (int n = 0; n < 4; ++n) {
      size_t base = (size_t)(m0 + wr + m * 16 + cr) * ldc + (n0 + wc + n * 16 + cc);
#pragma unroll
      for (int j = 0; j < 4; ++j)
        C[base + (size_t)j * ldc] = f2bf(acc[m][n][j]);
    }
}

// ---- hidden-layer edge pass: f-state residual in bf16 (in place), logits ----
__global__ __launch_bounds__(256) void edge_hidden(
    const u16* __restrict__ t_ni, const u16* __restrict__ t_nj, const u16* __restrict__ fW,
    const int* __restrict__ src, const int* __restrict__ dst,
    const float* __restrict__ bias, const float* __restrict__ attn,
    u16* __restrict__ f_bf, float* __restrict__ exb) {
  int e = blockIdx.x * 4 + (threadIdx.x >> 6);
  if (e >= NE) return;
  int lane = threadIdx.x & 63;
  int is = src[e], id = dst[e];
  int c = lane * 4;
  u16x4 va = *(const u16x4*)(t_ni + (size_t)is * 256 + c);
  u16x4 vb = *(const u16x4*)(t_nj + (size_t)id * 256 + c);
  u16x4 vc = *(const u16x4*)(fW + (size_t)e * 256 + c);
  f32x4 vbi = *(const f32x4*)(bias + c);
  int h = lane >> 3;
  f32x4 vat = *(const f32x4*)(attn + h * 32 + (lane & 7) * 4);
  size_t idx0 = (size_t)e * 256 + c;
  u16x4 fo = *(u16x4*)(f_bf + idx0);
  float part = 0.f;
#pragma unroll
  for (int j = 0; j < 4; ++j) {
    float y = bf2f(va[j]) + bf2f(vb[j]) + bf2f(vc[j]) + vbi[j];
    y = y > 0.f ? y : 0.01f * y;           // leaky_relu
    part += y * vat[j];                    // attention logit partial
    float el = y > 0.f ? y : expm1f(y);    // elu(f_out)
    fo[j] = f2bf(bf2f(fo[j]) + el);        // residual in bf16
  }
  *(u16x4*)(f_bf + idx0) = fo;
  part += __shfl_xor(part, 1);
  part += __shfl_xor(part, 2);
  part += __shfl_xor(part, 4);             // reduce the 8 lanes of this head
  part = fminf(fmaxf(part, -30.f), 30.f);  // insurance: exp can never overflow
  if ((lane & 7) == 0) exb[(size_t)e * 8 + h] = expf(part);
}

// ---- hidden gather: softmax denom + weighted msg + elu + residual (no atomics) ----
__global__ __launch_bounds__(256) void node_gather_hidden(
    const u16* __restrict__ t_node, const int* __restrict__ row_ptr,
    const int* __restrict__ cs_e, const int* __restrict__ cs_src,
    const float* __restrict__ exb, float* __restrict__ n_cur, u16* __restrict__ n_bf) {
  int node = blockIdx.x * 4 + (threadIdx.x >> 6);
  if (node >= NN) return;
  int lane = threadIdx.x & 63;
  int c = lane * 4, h = lane >> 3;
  int beg = row_ptr[node], end = row_ptr[node + 1];
  float denom = 0.f;
  float acc[4] = {0.f, 0.f, 0.f, 0.f};
  for (int p = beg; p < end; ++p) {
    float a = exb[(size_t)cs_e[p] * 8 + h];
    denom += a;
    u16x4 hv = *(const u16x4*)(t_node + (size_t)cs_src[p] * 256 + c);
#pragma unroll
    for (int j = 0; j < 4; ++j) acc[j] += a * bf2f(hv[j]);
  }
  float inv = denom > 0.f ? 1.f / denom : 0.f;
  size_t i0 = (size_t)node * 256 + c;
  f32x4 nv = *(f32x4*)(n_cur + i0);
  u16x4 bv;
#pragma unroll
  for (int j = 0; j < 4; ++j) {
    float t = acc[j] * inv;
    t = t > 0.f ? t : expm1f(t);   // elu
    nv[j] += t;
    bv[j] = f2bf(nv[j]);
  }
  *(f32x4*)(n_cur + i0) = nv;
  *(u16x4*)(n_bf + i0) = bv;
}

// ---- final-layer edge pass, ALL 8 heads: out_f = f_state + mean_h(y), exb per head ----
__global__ __launch_bounds__(256) void edge_final_all(
    int e0, const u16* __restrict__ t_ni, const u16* __restrict__ t_nj,
    const u16* __restrict__ fWc, const int* __restrict__ src, const int* __restrict__ dst,
    const float* __restrict__ bias, const float* __restrict__ attn,
    const u16* __restrict__ f_bf, float* __restrict__ out_f, float* __restrict__ exb) {
  int ec = blockIdx.x * 4 + (threadIdx.x >> 6);
  if (ec >= ECH) return;
  int e = e0 + ec;
  int lane = threadIdx.x & 63;
  int is = src[e], id = dst[e];
  int c = lane * 4;
  float total[4] = {0.f, 0.f, 0.f, 0.f};
#pragma unroll
  for (int h = 0; h < 8; ++h) {
    u16x4 va = *(const u16x4*)(t_ni + (size_t)is * 2048 + h * 256 + c);
    u16x4 vb = *(const u16x4*)(t_nj + (size_t)id * 2048 + h * 256 + c);
    u16x4 vc = *(const u16x4*)(fWc + (size_t)ec * 2048 + h * 256 + c);
    f32x4 vbi = *(const f32x4*)(bias + h * 256 + c);
    f32x4 vat = *(const f32x4*)(attn + h * 256 + c);
    float part = 0.f;
#pragma unroll
    for (int j = 0; j < 4; ++j) {
      float y = bf2f(va[j]) + bf2f(vb[j]) + bf2f(vc[j]) + vbi[j];
      y = y > 0.f ? y : 0.01f * y;   // leaky_relu; final: head-mean, no elu
      part += y * vat[j];
      total[j] += 0.125f * y;
    }
#pragma unroll
    for (int m = 1; m < 64; m <<= 1) part += __shfl_xor(part, m);
    part = fminf(fmaxf(part, -30.f), 30.f);
    if (lane == 0) exb[(size_t)e * 8 + h] = expf(part);
  }
  size_t i0 = (size_t)e * 256 + c;
  u16x4 fs = *(const u16x4*)(f_bf + i0);
  f32x4 o;
#pragma unroll
  for (int j = 0; j < 4; ++j) o[j] = bf2f(fs[j]) + total[j];
  *(f32x4*)(out_f + i0) = o;
}

// ---- final gather, ALL 8 heads, p-outer/h-inner one-pass (8-wide MLP) ----
// out_n = n_cur + (1/8) * sum_h (sum_p exb[p,h]*row[p,h]) / denom_h
__global__ __launch_bounds__(256) void node_gather_final_all(
    const u16* __restrict__ t_node, const int* __restrict__ row_ptr,
    const int* __restrict__ cs_e, const int* __restrict__ cs_src,
    const float* __restrict__ exb, const float* __restrict__ n_cur,
    float* __restrict__ out_n) {
  int node = blockIdx.x * 4 + (threadIdx.x >> 6);
  if (node >= NN) return;
  int lane = threadIdx.x & 63;
  int c = lane * 4;
  int beg = row_ptr[node], end = row_ptr[node + 1];
  float dh[8] = {};
  float acc[8][4] = {};
  for (int p = beg; p < end; ++p) {
    int e = cs_e[p];
    int s = cs_src[p];
    const u16* rowb = t_node + (size_t)s * 2048;
    const float* eb = exb + (size_t)e * 8;
    float a[8];
    u16x4 rv[8];
#pragma unroll
    for (int h = 0; h < 8; ++h) {
      a[h] = eb[h];
      rv[h] = *(const u16x4*)(rowb + h * 256 + c);   // 8 independent loads in flight
    }
#pragma unroll
    for (int h = 0; h < 8; ++h) {
      dh[h] += a[h];
#pragma unroll
      for (int j = 0; j < 4; ++j) acc[h][j] += a[h] * bf2f(rv[h][j]);
    }
  }
  float total[4] = {0.f, 0.f, 0.f, 0.f};
#pragma unroll
  for (int h = 0; h < 8; ++h) {
    float inv = dh[h] > 0.f ? 0.125f / dh[h] : 0.f;
#pragma unroll
    for (int j = 0; j < 4; ++j) total[j] += acc[h][j] * inv;
  }
  size_t i0 = (size_t)node * 256 + c;
  f32x4 nv = *(const f32x4*)(n_cur + i0);
#pragma unroll
  for (int j = 0; j < 4; ++j) nv[j] += total[j];
  *(f32x4*)(out_n + i0) = nv;
}

extern "C" void kernel_launch(void* const* d_in, const int* in_sizes, int n_in,
                              void* d_out, int out_size, void* d_ws, size_t ws_size,
                              hipStream_t stream) {
  const float* nfeat   = (const float*)d_in[0];
  const float* efeat   = (const float*)d_in[1];
  const int*   src     = (const int*)d_in[2];
  const int*   dst     = (const int*)d_in[3];
  const float* Wnode_h = (const float*)d_in[4];
  const float* Wni_h   = (const float*)d_in[5];
  const float* Wnj_h   = (const float*)d_in[6];
  const float* Wfij_h  = (const float*)d_in[7];
  const float* attn_h  = (const float*)d_in[8];
  const float* bias_h  = (const float*)d_in[9];
  const float* Wnode_l = (const float*)d_in[10];
  const float* Wni_l   = (const float*)d_in[11];
  const float* Wnj_l   = (const float*)d_in[12];
  const float* Wfij_l  = (const float*)d_in[13];
  const float* attn_l  = (const float*)d_in[14];
  const float* bias_l  = (const float*)d_in[15];

  // workspace ~262 MB (ws_size ≈ 327 MB per harness poison-fill evidence)
  char* ws = (char*)d_ws;
  size_t off = 0;
  auto alloc = [&](size_t b) { char* p = ws + off; off += (b + 255) & ~(size_t)255; return p; };
  float* n_cur = (float*)alloc((size_t)NN * 256 * 4);     // node state (f32)
  u16* n_bf    = (u16*)alloc((size_t)NN * 256 * 2);       // bf16 mirror (GEMM A)
  u16* f_bf    = (u16*)alloc((size_t)NE * 256 * 2);       // edge state (bf16)
  u16* t_ni    = (u16*)alloc((size_t)NN * 2048 * 2);      // final-layer node tables [NN,2048]
  u16* t_nj    = (u16*)alloc((size_t)NN * 2048 * 2);
  u16* t_node  = (u16*)alloc((size_t)NN * 2048 * 2);
  u16* fW      = (u16*)alloc((size_t)NE * 256 * 2);       // hidden fW [NE,256]; final chunk [ECH,2048] aliases
  float* exb   = (float*)alloc((size_t)NE * 8 * 4);       // exp(logits)
  u16* WT      = (u16*)alloc((size_t)4 * 65536 * 2);      // hidden transposed weights
  u16* WTF     = (u16*)alloc((size_t)4 * 524288 * 2);     // final transposed weights
  int* deg     = (int*)alloc((size_t)NN * 4);             // CSR
  int* cursor  = (int*)alloc((size_t)NN * 4);
  int* row_ptr = (int*)alloc((size_t)(NN + 1) * 4);
  int* cs_e    = (int*)alloc((size_t)NE * 4);
  int* cs_src  = (int*)alloc((size_t)NE * 4);

  u16* WT_node = WT;
  u16* WT_ni   = WT + 65536;
  u16* WT_nj   = WT + 2 * 65536;
  u16* WT_fij  = WT + 3 * 65536;
  u16* WTF_node = WTF;
  u16* WTF_ni   = WTF + (size_t)1 * 524288;
  u16* WTF_nj   = WTF + (size_t)2 * 524288;
  u16* WTF_fij  = WTF + (size_t)3 * 524288;

  float* out_n = (float*)d_out;
  float* out_f = out_n + (size_t)NN * 256;

  // CSR build (reused by all message passes)
  hipMemsetAsync(deg, 0, (size_t)NN * 4, stream);
  deg_hist<<<(NE + 255) / 256, 256, 0, stream>>>(dst, deg);
  scan_deg<<<1, 1024, 0, stream>>>(deg, row_ptr, cursor);
  csr_fill<<<(NE + 255) / 256, 256, 0, stream>>>(src, dst, cursor, cs_e, cs_src);

  cast_init<<<1024, 256, 0, stream>>>(nfeat, n_cur, n_bf, NN * 256 / 4);
  cast_bf<<<2048, 256, 0, stream>>>(efeat, f_bf, NE * 256 / 4);

  // hidden layers (t_ni/t_nj/t_node used as [NN,256] tables here)
  for (int l = 0; l < 2; ++l) {
    transpose4<<<dim3(16, 16, 4), dim3(16, 16), 0, stream>>>(
        Wnode_h + (size_t)l * 65536, Wni_h + (size_t)l * 65536,
        Wnj_h + (size_t)l * 65536, Wfij_h + (size_t)l * 65536, 256, 65536, WT);
    gemm_abt<<<dim3(2, 125, 3), 256, 0, stream>>>(n_bf, WT_ni, WT_nj, WT_node,
                                                  t_ni, t_nj, t_node, 256);
    gemm_abt<<<dim3(2, 500, 1), 256, 0, stream>>>(f_bf, WT_fij, WT_fij, WT_fij,
                                                  fW, fW, fW, 256);
    edge_hidden<<<16000, 256, 0, stream>>>(t_ni, t_nj, fW, src, dst,
        bias_h + (size_t)l * 256, attn_h + (size_t)l * 256, f_bf, exb);
    node_gather_hidden<<<4000, 256, 0, stream>>>(t_node, row_ptr, cs_e, cs_src, exb, n_cur, n_bf);
  }

  // final layer: full-width node tables once, then edge-chunked f-GEMM + all-heads edge pass
  transpose4<<<dim3(128, 16, 4), dim3(16, 16), 0, stream>>>(
      Wnode_l, Wni_l, Wnj_l, Wfij_l, 2048, 524288, WTF);
  gemm_abt<<<dim3(16, 125, 3), 256, 0, stream>>>(n_bf, WTF_ni, WTF_nj, WTF_node,
                                                 t_ni, t_nj, t_node, 2048);
  for (int cchunk = 0; cchunk < NE / ECH; ++cchunk) {
    const u16* Ac = f_bf + (size_t)cchunk * ECH * 256;
    gemm_abt<<<dim3(16, ECH / 128, 1), 256, 0, stream>>>(Ac, WTF_fij, WTF_fij, WTF_fij,
                                                         fW, fW, fW, 2048);
    edge_final_all<<<ECH / 4, 256, 0, stream>>>(cchunk * ECH, t_ni, t_nj, fW, src, dst,
                                                bias_l, attn_l, f_bf, out_f, exb);
  }
  node_gather_final_all<<<4000, 256, 0, stream>>>(t_node, row_ptr, cs_e, cs_src,
                                                  exb, n_cur, out_n);
}

// Round 8
// 716.581 us; speedup vs baseline: 4.1040x; 1.0664x over previous
//
#include <hip/hip_runtime.h>

typedef unsigned short u16;
typedef __attribute__((ext_vector_type(4))) unsigned short u16x4;
typedef __attribute__((ext_vector_type(4))) float f32x4;
typedef __attribute__((ext_vector_type(8))) __bf16 bf16x8;

#define NN 16000
#define NE 64000
#define ECH 6400   // final-layer edge chunk (10 chunks)

__device__ __forceinline__ float bf2f(u16 b) {
  union { unsigned int u; float f; } v; v.u = ((unsigned int)b) << 16; return v.f;
}
__device__ __forceinline__ u16 f2bf(float x) {
  union { float f; unsigned int u; } v; v.f = x;
  unsigned int r = v.u + 0x7FFFu + ((v.u >> 16) & 1u);
  return (u16)(r >> 16);
}

// ---------------- node init: f32 working copy + bf16 mirror ----------------
__global__ void cast_init(const float* __restrict__ in, float* __restrict__ outf,
                          u16* __restrict__ outb, int n4) {
  for (int i = blockIdx.x * blockDim.x + threadIdx.x; i < n4; i += gridDim.x * blockDim.x) {
    f32x4 v = ((const f32x4*)in)[i];
    u16x4 b;
#pragma unroll
    for (int j = 0; j < 4; ++j) b[j] = f2bf(v[j]);
    ((f32x4*)outf)[i] = v;
    ((u16x4*)outb)[i] = b;
  }
}

// ---------------- edge init: bf16 state only ----------------
__global__ void cast_bf(const float* __restrict__ in, u16* __restrict__ outb, int n4) {
  for (int i = blockIdx.x * blockDim.x + threadIdx.x; i < n4; i += gridDim.x * blockDim.x) {
    f32x4 v = ((const f32x4*)in)[i];
    u16x4 b;
#pragma unroll
    for (int j = 0; j < 4; ++j) b[j] = f2bf(v[j]);
    ((u16x4*)outb)[i] = b;
  }
}

// ---------------- CSR build ----------------
__global__ void deg_hist(const int* __restrict__ dst, int* __restrict__ deg) {
  int e = blockIdx.x * 256 + threadIdx.x;
  if (e < NE) atomicAdd(&deg[dst[e]], 1);
}

__global__ __launch_bounds__(1024) void scan_deg(const int* __restrict__ deg,
                                                 int* __restrict__ row_ptr,
                                                 int* __restrict__ cursor) {
  __shared__ int lds[1024];
  int t = threadIdx.x;
  int base = t * 16;
  int v[16];
  int s = 0;
#pragma unroll
  for (int j = 0; j < 16; ++j) {
    int idx = base + j;
    v[j] = idx < NN ? deg[idx] : 0;
    s += v[j];
  }
  lds[t] = s;
  __syncthreads();
  for (int d = 1; d < 1024; d <<= 1) {
    int x = t >= d ? lds[t - d] : 0;
    __syncthreads();
    lds[t] += x;
    __syncthreads();
  }
  int run = lds[t] - s;
  for (int j = 0; j < 16; ++j) {
    int idx = base + j;
    if (idx < NN) { row_ptr[idx] = run; cursor[idx] = run; run += v[j]; }
  }
  if (t == 1023) row_ptr[NN] = run;
}

__global__ void csr_fill(const int* __restrict__ src, const int* __restrict__ dst,
                         int* __restrict__ cursor, int* __restrict__ cs_e,
                         int* __restrict__ cs_src) {
  int e = blockIdx.x * 256 + threadIdx.x;
  if (e >= NE) return;
  int pos = atomicAdd(&cursor[dst[e]], 1);
  cs_e[pos] = e;
  cs_src[pos] = src[e];
}

// ---- weight transpose + bf16 cast: WT[z*osz + n*256 + k] = bf16(W[k][n]) ----
__global__ void transpose4(const float* __restrict__ W0, const float* __restrict__ W1,
                           const float* __restrict__ W2, const float* __restrict__ W3,
                           int ld, int osz, u16* __restrict__ WT) {
  __shared__ float t[16][17];
  int z = blockIdx.z;
  const float* W = z == 0 ? W0 : (z == 1 ? W1 : (z == 2 ? W2 : W3));
  u16* O = WT + (size_t)z * osz;
  int n0 = blockIdx.x * 16, k0 = blockIdx.y * 16;
  int tx = threadIdx.x, ty = threadIdx.y;
  t[ty][tx] = W[(size_t)(k0 + ty) * ld + n0 + tx];
  __syncthreads();
  O[(size_t)(n0 + ty) * 256 + k0 + tx] = f2bf(t[tx][ty]);
}

// ------------- bf16 GEMM, 2-phase pipelined, T2 LDS-swizzled, T1 XCD-swizzled -------------
// C[M,ldc] = A[M,256] @ B (B^T given). grid = (ldc/128, M/128, nmat).
// LDS swizzle (both-sides): 16B slot s of row r holds global slot s^(r&7); ds_read XORs the
// same permutation => bit-identical math, conflict-free banks (8 dwords/bank = b128 minimum).
// XCD swizzle (bijective, m204): contiguous wg-chunks per XCD => A-slice+B L2-resident per XCD.
__global__ __launch_bounds__(256) void gemm_abt(
    const u16* __restrict__ A,
    const u16* __restrict__ BT0, const u16* __restrict__ BT1, const u16* __restrict__ BT2,
    u16* __restrict__ C0, u16* __restrict__ C1, u16* __restrict__ C2, int ldc) {
  const int bz = blockIdx.z;
  const u16* BT = bz == 0 ? BT0 : (bz == 1 ? BT1 : BT2);
  u16* C = bz == 0 ? C0 : (bz == 1 ? C1 : C2);
  // bijective XCD swizzle on the xy-plane (per z-slice; chunk-contiguity is what matters)
  const int nx = gridDim.x;
  const int nwg = nx * gridDim.y;
  int bid = blockIdx.y * nx + blockIdx.x;
  int q = nwg >> 3, r = nwg & 7;
  int xcd = bid & 7, idx = bid >> 3;
  int wg = (xcd < r) ? (xcd * (q + 1) + idx) : (r * (q + 1) + (xcd - r) * q + idx);
  const int m0 = (wg / nx) * 128;
  const int n0 = (wg % nx) * 128;
  __shared__ u16 lA[2][128 * 64];
  __shared__ u16 lB[2][128 * 64];
  const int tid = threadIdx.x;
  const int lane = tid & 63;
  const int wid = tid >> 6;
  const int wr = (wid >> 1) * 64;
  const int wc = (wid & 1) * 64;
  const int srow = tid >> 3;                       // staged row (+i*32); row&7 = srow&7
  const int sdst = (tid & 7) * 8;                  // linear LDS slot (16B units *8 elems)
  const int ssrc = (((tid & 7) ^ (srow & 7))) * 8; // pre-swizzled global slot
  const int sx = (lane >> 4) ^ (lane & 7);         // read-side slot XOR (row&7 == lane&7)
  f32x4 acc[4][4] = {};
#define STAGE(buf, kb)                                                                         \
  {                                                                                            \
    _Pragma("unroll") for (int i = 0; i < 4; ++i) {                                            \
      const int row = srow + i * 32;                                                           \
      __builtin_amdgcn_global_load_lds(                                                        \
          (const __attribute__((address_space(1))) void*)(A + (size_t)(m0 + row) * 256 + (kb) + ssrc), \
          (__attribute__((address_space(3))) void*)(lA[buf] + row * 64 + sdst), 16, 0, 0);     \
      __builtin_amdgcn_global_load_lds(                                                        \
          (const __attribute__((address_space(1))) void*)(BT + (size_t)(n0 + row) * 256 + (kb) + ssrc), \
          (__attribute__((address_space(3))) void*)(lB[buf] + row * 64 + sdst), 16, 0, 0);     \
    }                                                                                          \
  }
  STAGE(0, 0)
  __syncthreads();
#pragma unroll
  for (int t = 0; t < 4; ++t) {
    if (t < 3) STAGE((t + 1) & 1, (t + 1) * 64)
    const u16* pA = lA[t & 1];
    const u16* pB = lB[t & 1];
#pragma unroll
    for (int kk = 0; kk < 2; ++kk) {
      const int sw = ((kk << 2) ^ sx) * 8;   // swizzled slot offset (elements)
      bf16x8 af[4], bfr[4];
#pragma unroll
      for (int m = 0; m < 4; ++m)
        af[m] = *(const bf16x8*)(pA + (wr + m * 16 + (lane & 15)) * 64 + sw);
#pragma unroll
      for (int n = 0; n < 4; ++n)
        bfr[n] = *(const bf16x8*)(pB + (wc + n * 16 + (lane & 15)) * 64 + sw);
#pragma unroll
      for (int m = 0; m < 4; ++m)
#pragma unroll
        for (int n = 0; n < 4; ++n)
          acc[m][n] = __builtin_amdgcn_mfma_f32_16x16x32_bf16(af[m], bfr[n], acc[m][n], 0, 0, 0);
    }
    __syncthreads();
  }
#undef STAGE
  const int cr = (lane >> 4) * 4;  // C/D: col = lane&15, row = (lane>>4)*4 + reg
  const int cc = lane & 15;
#pragma unroll
  for (int m = 0; m < 4; ++m)
#pragma unroll
    for (int n = 0; n < 4; ++n) {
      size_t base = (size_t)(m0 + wr + m * 16 + cr) * ldc + (n0 + wc + n * 16 + cc);
#pragma unroll
      for (int j = 0; j < 4; ++j)
        C[base + (size_t)j * ldc] = f2bf(acc[m][n][j]);
    }
}

// ---- hidden-layer edge pass: f-state residual in bf16 (in place), logits ----
__global__ __launch_bounds__(256) void edge_hidden(
    const u16* __restrict__ t_ni, const u16* __restrict__ t_nj, const u16* __restrict__ fW,
    const int* __restrict__ src, const int* __restrict__ dst,
    const float* __restrict__ bias, const float* __restrict__ attn,
    u16* __restrict__ f_bf, float* __restrict__ exb) {
  int e = blockIdx.x * 4 + (threadIdx.x >> 6);
  if (e >= NE) return;
  int lane = threadIdx.x & 63;
  int is = src[e], id = dst[e];
  int c = lane * 4;
  u16x4 va = *(const u16x4*)(t_ni + (size_t)is * 256 + c);
  u16x4 vb = *(const u16x4*)(t_nj + (size_t)id * 256 + c);
  u16x4 vc = *(const u16x4*)(fW + (size_t)e * 256 + c);
  f32x4 vbi = *(const f32x4*)(bias + c);
  int h = lane >> 3;
  f32x4 vat = *(const f32x4*)(attn + h * 32 + (lane & 7) * 4);
  size_t idx0 = (size_t)e * 256 + c;
  u16x4 fo = *(u16x4*)(f_bf + idx0);
  float part = 0.f;
#pragma unroll
  for (int j = 0; j < 4; ++j) {
    float y = bf2f(va[j]) + bf2f(vb[j]) + bf2f(vc[j]) + vbi[j];
    y = y > 0.f ? y : 0.01f * y;           // leaky_relu
    part += y * vat[j];                    // attention logit partial
    float el = y > 0.f ? y : expm1f(y);    // elu(f_out)
    fo[j] = f2bf(bf2f(fo[j]) + el);        // residual in bf16
  }
  *(u16x4*)(f_bf + idx0) = fo;
  part += __shfl_xor(part, 1);
  part += __shfl_xor(part, 2);
  part += __shfl_xor(part, 4);             // reduce the 8 lanes of this head
  part = fminf(fmaxf(part, -30.f), 30.f);  // insurance: exp can never overflow
  if ((lane & 7) == 0) exb[(size_t)e * 8 + h] = expf(part);
}

// ---- hidden gather: softmax denom + weighted msg + elu + residual (no atomics) ----
__global__ __launch_bounds__(256) void node_gather_hidden(
    const u16* __restrict__ t_node, const int* __restrict__ row_ptr,
    const int* __restrict__ cs_e, const int* __restrict__ cs_src,
    const float* __restrict__ exb, float* __restrict__ n_cur, u16* __restrict__ n_bf) {
  int node = blockIdx.x * 4 + (threadIdx.x >> 6);
  if (node >= NN) return;
  int lane = threadIdx.x & 63;
  int c = lane * 4, h = lane >> 3;
  int beg = row_ptr[node], end = row_ptr[node + 1];
  float denom = 0.f;
  float acc[4] = {0.f, 0.f, 0.f, 0.f};
  for (int p = beg; p < end; ++p) {
    float a = exb[(size_t)cs_e[p] * 8 + h];
    denom += a;
    u16x4 hv = *(const u16x4*)(t_node + (size_t)cs_src[p] * 256 + c);
#pragma unroll
    for (int j = 0; j < 4; ++j) acc[j] += a * bf2f(hv[j]);
  }
  float inv = denom > 0.f ? 1.f / denom : 0.f;
  size_t i0 = (size_t)node * 256 + c;
  f32x4 nv = *(f32x4*)(n_cur + i0);
  u16x4 bv;
#pragma unroll
  for (int j = 0; j < 4; ++j) {
    float t = acc[j] * inv;
    t = t > 0.f ? t : expm1f(t);   // elu
    nv[j] += t;
    bv[j] = f2bf(nv[j]);
  }
  *(f32x4*)(n_cur + i0) = nv;
  *(u16x4*)(n_bf + i0) = bv;
}

// ---- final-layer edge pass, ALL 8 heads: out_f = f_state + mean_h(y), exb per head ----
__global__ __launch_bounds__(256) void edge_final_all(
    int e0, const u16* __restrict__ t_ni, const u16* __restrict__ t_nj,
    const u16* __restrict__ fWc, const int* __restrict__ src, const int* __restrict__ dst,
    const float* __restrict__ bias, const float* __restrict__ attn,
    const u16* __restrict__ f_bf, float* __restrict__ out_f, float* __restrict__ exb) {
  int ec = blockIdx.x * 4 + (threadIdx.x >> 6);
  if (ec >= ECH) return;
  int e = e0 + ec;
  int lane = threadIdx.x & 63;
  int is = src[e], id = dst[e];
  int c = lane * 4;
  float total[4] = {0.f, 0.f, 0.f, 0.f};
#pragma unroll
  for (int h = 0; h < 8; ++h) {
    u16x4 va = *(const u16x4*)(t_ni + (size_t)is * 2048 + h * 256 + c);
    u16x4 vb = *(const u16x4*)(t_nj + (size_t)id * 2048 + h * 256 + c);
    u16x4 vc = *(const u16x4*)(fWc + (size_t)ec * 2048 + h * 256 + c);
    f32x4 vbi = *(const f32x4*)(bias + h * 256 + c);
    f32x4 vat = *(const f32x4*)(attn + h * 256 + c);
    float part = 0.f;
#pragma unroll
    for (int j = 0; j < 4; ++j) {
      float y = bf2f(va[j]) + bf2f(vb[j]) + bf2f(vc[j]) + vbi[j];
      y = y > 0.f ? y : 0.01f * y;   // leaky_relu; final: head-mean, no elu
      part += y * vat[j];
      total[j] += 0.125f * y;
    }
#pragma unroll
    for (int m = 1; m < 64; m <<= 1) part += __shfl_xor(part, m);
    part = fminf(fmaxf(part, -30.f), 30.f);
    if (lane == 0) exb[(size_t)e * 8 + h] = expf(part);
  }
  size_t i0 = (size_t)e * 256 + c;
  u16x4 fs = *(const u16x4*)(f_bf + i0);
  f32x4 o;
#pragma unroll
  for (int j = 0; j < 4; ++j) o[j] = bf2f(fs[j]) + total[j];
  *(f32x4*)(out_f + i0) = o;
}

// ---- final gather, ALL 8 heads, p-outer/h-inner one-pass ----
__global__ __launch_bounds__(256) void node_gather_final_all(
    const u16* __restrict__ t_node, const int* __restrict__ row_ptr,
    const int* __restrict__ cs_e, const int* __restrict__ cs_src,
    const float* __restrict__ exb, const float* __restrict__ n_cur,
    float* __restrict__ out_n) {
  int node = blockIdx.x * 4 + (threadIdx.x >> 6);
  if (node >= NN) return;
  int lane = threadIdx.x & 63;
  int c = lane * 4;
  int beg = row_ptr[node], end = row_ptr[node + 1];
  float dh[8] = {};
  float acc[8][4] = {};
  for (int p = beg; p < end; ++p) {
    int e = cs_e[p];
    int s = cs_src[p];
    const u16* rowb = t_node + (size_t)s * 2048;
    const float* eb = exb + (size_t)e * 8;
    float a[8];
    u16x4 rv[8];
#pragma unroll
    for (int h = 0; h < 8; ++h) {
      a[h] = eb[h];
      rv[h] = *(const u16x4*)(rowb + h * 256 + c);   // 8 independent loads in flight
    }
#pragma unroll
    for (int h = 0; h < 8; ++h) {
      dh[h] += a[h];
#pragma unroll
      for (int j = 0; j < 4; ++j) acc[h][j] += a[h] * bf2f(rv[h][j]);
    }
  }
  float total[4] = {0.f, 0.f, 0.f, 0.f};
#pragma unroll
  for (int h = 0; h < 8; ++h) {
    float inv = dh[h] > 0.f ? 0.125f / dh[h] : 0.f;
#pragma unroll
    for (int j = 0; j < 4; ++j) total[j] += acc[h][j] * inv;
  }
  size_t i0 = (size_t)node * 256 + c;
  f32x4 nv = *(const f32x4*)(n_cur + i0);
#pragma unroll
  for (int j = 0; j < 4; ++j) nv[j] += total[j];
  *(f32x4*)(out_n + i0) = nv;
}

extern "C" void kernel_launch(void* const* d_in, const int* in_sizes, int n_in,
                              void* d_out, int out_size, void* d_ws, size_t ws_size,
                              hipStream_t stream) {
  const float* nfeat   = (const float*)d_in[0];
  const float* efeat   = (const float*)d_in[1];
  const int*   src     = (const int*)d_in[2];
  const int*   dst     = (const int*)d_in[3];
  const float* Wnode_h = (const float*)d_in[4];
  const float* Wni_h   = (const float*)d_in[5];
  const float* Wnj_h   = (const float*)d_in[6];
  const float* Wfij_h  = (const float*)d_in[7];
  const float* attn_h  = (const float*)d_in[8];
  const float* bias_h  = (const float*)d_in[9];
  const float* Wnode_l = (const float*)d_in[10];
  const float* Wni_l   = (const float*)d_in[11];
  const float* Wnj_l   = (const float*)d_in[12];
  const float* Wfij_l  = (const float*)d_in[13];
  const float* attn_l  = (const float*)d_in[14];
  const float* bias_l  = (const float*)d_in[15];

  // workspace ~262 MB (ws_size ≈ 327 MB per harness poison-fill evidence)
  char* ws = (char*)d_ws;
  size_t off = 0;
  auto alloc = [&](size_t b) { char* p = ws + off; off += (b + 255) & ~(size_t)255; return p; };
  float* n_cur = (float*)alloc((size_t)NN * 256 * 4);     // node state (f32)
  u16* n_bf    = (u16*)alloc((size_t)NN * 256 * 2);       // bf16 mirror (GEMM A)
  u16* f_bf    = (u16*)alloc((size_t)NE * 256 * 2);       // edge state (bf16)
  u16* t_ni    = (u16*)alloc((size_t)NN * 2048 * 2);      // final-layer node tables [NN,2048]
  u16* t_nj    = (u16*)alloc((size_t)NN * 2048 * 2);
  u16* t_node  = (u16*)alloc((size_t)NN * 2048 * 2);
  u16* fW      = (u16*)alloc((size_t)NE * 256 * 2);       // hidden fW [NE,256]; final chunk [ECH,2048] aliases
  float* exb   = (float*)alloc((size_t)NE * 8 * 4);       // exp(logits)
  u16* WT      = (u16*)alloc((size_t)4 * 65536 * 2);      // hidden transposed weights
  u16* WTF     = (u16*)alloc((size_t)4 * 524288 * 2);     // final transposed weights
  int* deg     = (int*)alloc((size_t)NN * 4);             // CSR
  int* cursor  = (int*)alloc((size_t)NN * 4);
  int* row_ptr = (int*)alloc((size_t)(NN + 1) * 4);
  int* cs_e    = (int*)alloc((size_t)NE * 4);
  int* cs_src  = (int*)alloc((size_t)NE * 4);

  u16* WT_node = WT;
  u16* WT_ni   = WT + 65536;
  u16* WT_nj   = WT + 2 * 65536;
  u16* WT_fij  = WT + 3 * 65536;
  u16* WTF_node = WTF;
  u16* WTF_ni   = WTF + (size_t)1 * 524288;
  u16* WTF_nj   = WTF + (size_t)2 * 524288;
  u16* WTF_fij  = WTF + (size_t)3 * 524288;

  float* out_n = (float*)d_out;
  float* out_f = out_n + (size_t)NN * 256;

  // CSR build (reused by all message passes)
  hipMemsetAsync(deg, 0, (size_t)NN * 4, stream);
  deg_hist<<<(NE + 255) / 256, 256, 0, stream>>>(dst, deg);
  scan_deg<<<1, 1024, 0, stream>>>(deg, row_ptr, cursor);
  csr_fill<<<(NE + 255) / 256, 256, 0, stream>>>(src, dst, cursor, cs_e, cs_src);

  cast_init<<<1024, 256, 0, stream>>>(nfeat, n_cur, n_bf, NN * 256 / 4);
  cast_bf<<<2048, 256, 0, stream>>>(efeat, f_bf, NE * 256 / 4);

  // hidden layers (t_ni/t_nj/t_node used as [NN,256] tables here)
  for (int l = 0; l < 2; ++l) {
    transpose4<<<dim3(16, 16, 4), dim3(16, 16), 0, stream>>>(
        Wnode_h + (size_t)l * 65536, Wni_h + (size_t)l * 65536,
        Wnj_h + (size_t)l * 65536, Wfij_h + (size_t)l * 65536, 256, 65536, WT);
    gemm_abt<<<dim3(2, 125, 3), 256, 0, stream>>>(n_bf, WT_ni, WT_nj, WT_node,
                                                  t_ni, t_nj, t_node, 256);
    gemm_abt<<<dim3(2, 500, 1), 256, 0, stream>>>(f_bf, WT_fij, WT_fij, WT_fij,
                                                  fW, fW, fW, 256);
    edge_hidden<<<16000, 256, 0, stream>>>(t_ni, t_nj, fW, src, dst,
        bias_h + (size_t)l * 256, attn_h + (size_t)l * 256, f_bf, exb);
    node_gather_hidden<<<4000, 256, 0, stream>>>(t_node, row_ptr, cs_e, cs_src, exb, n_cur, n_bf);
  }

  // final layer: full-width node tables once, then edge-chunked f-GEMM + all-heads edge pass
  transpose4<<<dim3(128, 16, 4), dim3(16, 16), 0, stream>>>(
      Wnode_l, Wni_l, Wnj_l, Wfij_l, 2048, 524288, WTF);
  gemm_abt<<<dim3(16, 125, 3), 256, 0, stream>>>(n_bf, WTF_ni, WTF_nj, WTF_node,
                                                 t_ni, t_nj, t_node, 2048);
  for (int cchunk = 0; cchunk < NE / ECH; ++cchunk) {
    const u16* Ac = f_bf + (size_t)cchunk * ECH * 256;
    gemm_abt<<<dim3(16, ECH / 128, 1), 256, 0, stream>>>(Ac, WTF_fij, WTF_fij, WTF_fij,
                                                         fW, fW, fW, 2048);
    edge_final_all<<<ECH / 4, 256, 0, stream>>>(cchunk * ECH, t_ni, t_nj, fW, src, dst,
                                                bias_l, attn_l, f_bf, out_f, exb);
  }
  node_gather_final_all<<<4000, 256, 0, stream>>>(t_node, row_ptr, cs_e, cs_src,
                                                  exb, n_cur, out_n);
}

// Round 9
// 669.077 us; speedup vs baseline: 4.3953x; 1.0710x over previous
//
#include <hip/hip_runtime.h>

typedef unsigned short u16;
typedef __attribute__((ext_vector_type(4))) unsigned short u16x4;
typedef __attribute__((ext_vector_type(8))) unsigned short u16x8;
typedef __attribute__((ext_vector_type(4))) float f32x4;
typedef __attribute__((ext_vector_type(8))) __bf16 bf16x8;

#define NN 16000
#define NE 64000

__device__ __forceinline__ float bf2f(u16 b) {
  union { unsigned int u; float f; } v; v.u = ((unsigned int)b) << 16; return v.f;
}
__device__ __forceinline__ u16 f2bf(float x) {
  union { float f; unsigned int u; } v; v.f = x;
  unsigned int r = v.u + 0x7FFFu + ((v.u >> 16) & 1u);
  return (u16)(r >> 16);
}

// ---------------- node init: f32 working copy + bf16 mirror ----------------
__global__ void cast_init(const float* __restrict__ in, float* __restrict__ outf,
                          u16* __restrict__ outb, int n4) {
  for (int i = blockIdx.x * blockDim.x + threadIdx.x; i < n4; i += gridDim.x * blockDim.x) {
    f32x4 v = ((const f32x4*)in)[i];
    u16x4 b;
#pragma unroll
    for (int j = 0; j < 4; ++j) b[j] = f2bf(v[j]);
    ((f32x4*)outf)[i] = v;
    ((u16x4*)outb)[i] = b;
  }
}

// ---------------- edge init: bf16 state only ----------------
__global__ void cast_bf(const float* __restrict__ in, u16* __restrict__ outb, int n4) {
  for (int i = blockIdx.x * blockDim.x + threadIdx.x; i < n4; i += gridDim.x * blockDim.x) {
    f32x4 v = ((const f32x4*)in)[i];
    u16x4 b;
#pragma unroll
    for (int j = 0; j < 4; ++j) b[j] = f2bf(v[j]);
    ((u16x4*)outb)[i] = b;
  }
}

// ---------------- CSR build ----------------
__global__ void deg_hist(const int* __restrict__ dst, int* __restrict__ deg) {
  int e = blockIdx.x * 256 + threadIdx.x;
  if (e < NE) atomicAdd(&deg[dst[e]], 1);
}

__global__ __launch_bounds__(1024) void scan_deg(const int* __restrict__ deg,
                                                 int* __restrict__ row_ptr,
                                                 int* __restrict__ cursor) {
  __shared__ int lds[1024];
  int t = threadIdx.x;
  int base = t * 16;
  int v[16];
  int s = 0;
#pragma unroll
  for (int j = 0; j < 16; ++j) {
    int idx = base + j;
    v[j] = idx < NN ? deg[idx] : 0;
    s += v[j];
  }
  lds[t] = s;
  __syncthreads();
  for (int d = 1; d < 1024; d <<= 1) {
    int x = t >= d ? lds[t - d] : 0;
    __syncthreads();
    lds[t] += x;
    __syncthreads();
  }
  int run = lds[t] - s;
  for (int j = 0; j < 16; ++j) {
    int idx = base + j;
    if (idx < NN) { row_ptr[idx] = run; cursor[idx] = run; run += v[j]; }
  }
  if (t == 1023) row_ptr[NN] = run;
}

__global__ void csr_fill(const int* __restrict__ src, const int* __restrict__ dst,
                         int* __restrict__ cursor, int* __restrict__ cs_e,
                         int* __restrict__ cs_src) {
  int e = blockIdx.x * 256 + threadIdx.x;
  if (e >= NE) return;
  int pos = atomicAdd(&cursor[dst[e]], 1);
  cs_e[pos] = e;
  cs_src[pos] = src[e];
}

// ---- weight transpose + bf16 cast: WT[z*osz + n*256 + k] = bf16(W[k][n]) ----
__global__ void transpose4(const float* __restrict__ W0, const float* __restrict__ W1,
                           const float* __restrict__ W2, const float* __restrict__ W3,
                           int ld, int osz, u16* __restrict__ WT) {
  __shared__ float t[16][17];
  int z = blockIdx.z;
  const float* W = z == 0 ? W0 : (z == 1 ? W1 : (z == 2 ? W2 : W3));
  u16* O = WT + (size_t)z * osz;
  int n0 = blockIdx.x * 16, k0 = blockIdx.y * 16;
  int tx = threadIdx.x, ty = threadIdx.y;
  t[ty][tx] = W[(size_t)(k0 + ty) * ld + n0 + tx];
  __syncthreads();
  O[(size_t)(n0 + ty) * 256 + k0 + tx] = f2bf(t[tx][ty]);
}

// ------------- bf16 GEMM: 2-phase pipeline, T2 LDS swizzle, T1 XCD swizzle,
// ------------- LDS-staged coalesced C-write (16B/lane stores) -------------
// C[M,ldc] = A[M,256] @ B (B^T given). grid = (ldc/128, M/128, nmat).
__global__ __launch_bounds__(256) void gemm_abt(
    const u16* __restrict__ A,
    const u16* __restrict__ BT0, const u16* __restrict__ BT1, const u16* __restrict__ BT2,
    u16* __restrict__ C0, u16* __restrict__ C1, u16* __restrict__ C2, int ldc) {
  const int bz = blockIdx.z;
  const u16* BT = bz == 0 ? BT0 : (bz == 1 ? BT1 : BT2);
  u16* C = bz == 0 ? C0 : (bz == 1 ? C1 : C2);
  // bijective XCD swizzle (m204)
  const int nx = gridDim.x;
  const int nwg = nx * gridDim.y;
  int bid = blockIdx.y * nx + blockIdx.x;
  int q = nwg >> 3, r = nwg & 7;
  int xcd = bid & 7, idx = bid >> 3;
  int wg = (xcd < r) ? (xcd * (q + 1) + idx) : (r * (q + 1) + (xcd - r) * q + idx);
  const int m0 = (wg / nx) * 128;
  const int n0 = (wg % nx) * 128;
  // smem: K-loop dbuf (64KB) overlaid by C-staging (4 waves x 64x68 f32 = 69632B)
  __shared__ __attribute__((aligned(16))) char smem[69632];
  u16* lA = (u16*)smem;              // [2][8192]
  u16* lB = (u16*)(smem + 32768);    // [2][8192]
  const int tid = threadIdx.x;
  const int lane = tid & 63;
  const int wid = tid >> 6;
  const int wr = (wid >> 1) * 64;
  const int wc = (wid & 1) * 64;
  const int srow = tid >> 3;                       // staged row (+i*32)
  const int sdst = (tid & 7) * 8;                  // linear LDS slot
  const int ssrc = (((tid & 7) ^ (srow & 7))) * 8; // pre-swizzled global slot
  const int sx = (lane >> 4) ^ (lane & 7);         // read-side slot XOR
  f32x4 acc[4][4] = {};
#define STAGE(buf, kb)                                                                         \
  {                                                                                            \
    _Pragma("unroll") for (int i = 0; i < 4; ++i) {                                            \
      const int row = srow + i * 32;                                                           \
      __builtin_amdgcn_global_load_lds(                                                        \
          (const __attribute__((address_space(1))) void*)(A + (size_t)(m0 + row) * 256 + (kb) + ssrc), \
          (__attribute__((address_space(3))) void*)(lA + (buf) * 8192 + row * 64 + sdst), 16, 0, 0); \
      __builtin_amdgcn_global_load_lds(                                                        \
          (const __attribute__((address_space(1))) void*)(BT + (size_t)(n0 + row) * 256 + (kb) + ssrc), \
          (__attribute__((address_space(3))) void*)(lB + (buf) * 8192 + row * 64 + sdst), 16, 0, 0); \
    }                                                                                          \
  }
  STAGE(0, 0)
  __syncthreads();
#pragma unroll
  for (int t = 0; t < 4; ++t) {
    if (t < 3) STAGE((t + 1) & 1, (t + 1) * 64)
    const u16* pA = lA + (t & 1) * 8192;
    const u16* pB = lB + (t & 1) * 8192;
#pragma unroll
    for (int kk = 0; kk < 2; ++kk) {
      const int sw = ((kk << 2) ^ sx) * 8;
      bf16x8 af[4], bfr[4];
#pragma unroll
      for (int m = 0; m < 4; ++m)
        af[m] = *(const bf16x8*)(pA + (wr + m * 16 + (lane & 15)) * 64 + sw);
#pragma unroll
      for (int n = 0; n < 4; ++n)
        bfr[n] = *(const bf16x8*)(pB + (wc + n * 16 + (lane & 15)) * 64 + sw);
#pragma unroll
      for (int m = 0; m < 4; ++m)
#pragma unroll
        for (int n = 0; n < 4; ++n)
          acc[m][n] = __builtin_amdgcn_mfma_f32_16x16x32_bf16(af[m], bfr[n], acc[m][n], 0, 0, 0);
    }
    __syncthreads();   // last iter: all LDS reads done -> staging may overwrite
  }
#undef STAGE
  // C-write via wave-private LDS staging: stride 68 f32 (write 2-way free; read at
  // b128 structural floor, 16B aligned). No barrier needed (per-wave region).
  const int cr = (lane >> 4) * 4;  // C/D: col = lane&15, row = (lane>>4)*4 + reg
  const int cc = lane & 15;
  float* stg = (float*)smem + wid * (64 * 68);
#pragma unroll
  for (int m = 0; m < 4; ++m)
#pragma unroll
    for (int n = 0; n < 4; ++n)
#pragma unroll
      for (int j = 0; j < 4; ++j)
        stg[(m * 16 + cr + j) * 68 + n * 16 + cc] = acc[m][n][j];
  const int rr = lane >> 3;
  const int c0 = (lane & 7) * 8;
#pragma unroll
  for (int p = 0; p < 8; ++p) {
    int row = p * 8 + rr;
    f32x4 v0 = *(const f32x4*)(stg + row * 68 + c0);
    f32x4 v1 = *(const f32x4*)(stg + row * 68 + c0 + 4);
    u16x8 o;
#pragma unroll
    for (int i = 0; i < 4; ++i) { o[i] = f2bf(v0[i]); o[4 + i] = f2bf(v1[i]); }
    *(u16x8*)(&C[(size_t)(m0 + wr + row) * ldc + (n0 + wc + c0)]) = o;
  }
}

// ---- hidden-layer edge pass: f-state residual in bf16 (in place), logits ----
__global__ __launch_bounds__(256) void edge_hidden(
    const u16* __restrict__ t_ni, const u16* __restrict__ t_nj, const u16* __restrict__ fW,
    const int* __restrict__ src, const int* __restrict__ dst,
    const float* __restrict__ bias, const float* __restrict__ attn,
    u16* __restrict__ f_bf, float* __restrict__ exb) {
  int e = blockIdx.x * 4 + (threadIdx.x >> 6);
  if (e >= NE) return;
  int lane = threadIdx.x & 63;
  int is = src[e], id = dst[e];
  int c = lane * 4;
  u16x4 va = *(const u16x4*)(t_ni + (size_t)is * 256 + c);
  u16x4 vb = *(const u16x4*)(t_nj + (size_t)id * 256 + c);
  u16x4 vc = *(const u16x4*)(fW + (size_t)e * 256 + c);
  f32x4 vbi = *(const f32x4*)(bias + c);
  int h = lane >> 3;
  f32x4 vat = *(const f32x4*)(attn + h * 32 + (lane & 7) * 4);
  size_t idx0 = (size_t)e * 256 + c;
  u16x4 fo = *(u16x4*)(f_bf + idx0);
  float part = 0.f;
#pragma unroll
  for (int j = 0; j < 4; ++j) {
    float y = bf2f(va[j]) + bf2f(vb[j]) + bf2f(vc[j]) + vbi[j];
    y = y > 0.f ? y : 0.01f * y;           // leaky_relu
    part += y * vat[j];                    // attention logit partial
    float el = y > 0.f ? y : expm1f(y);    // elu(f_out)
    fo[j] = f2bf(bf2f(fo[j]) + el);        // residual in bf16
  }
  *(u16x4*)(f_bf + idx0) = fo;
  part += __shfl_xor(part, 1);
  part += __shfl_xor(part, 2);
  part += __shfl_xor(part, 4);             // reduce the 8 lanes of this head
  part = fminf(fmaxf(part, -30.f), 30.f);  // insurance: exp can never overflow
  if ((lane & 7) == 0) exb[(size_t)e * 8 + h] = expf(part);
}

// ---- hidden gather: softmax denom + weighted msg + elu + residual (no atomics) ----
__global__ __launch_bounds__(256) void node_gather_hidden(
    const u16* __restrict__ t_node, const int* __restrict__ row_ptr,
    const int* __restrict__ cs_e, const int* __restrict__ cs_src,
    const float* __restrict__ exb, float* __restrict__ n_cur, u16* __restrict__ n_bf) {
  int node = blockIdx.x * 4 + (threadIdx.x >> 6);
  if (node >= NN) return;
  int lane = threadIdx.x & 63;
  int c = lane * 4, h = lane >> 3;
  int beg = row_ptr[node], end = row_ptr[node + 1];
  float denom = 0.f;
  float acc[4] = {0.f, 0.f, 0.f, 0.f};
  for (int p = beg; p < end; ++p) {
    float a = exb[(size_t)cs_e[p] * 8 + h];
    denom += a;
    u16x4 hv = *(const u16x4*)(t_node + (size_t)cs_src[p] * 256 + c);
#pragma unroll
    for (int j = 0; j < 4; ++j) acc[j] += a * bf2f(hv[j]);
  }
  float inv = denom > 0.f ? 1.f / denom : 0.f;
  size_t i0 = (size_t)node * 256 + c;
  f32x4 nv = *(f32x4*)(n_cur + i0);
  u16x4 bv;
#pragma unroll
  for (int j = 0; j < 4; ++j) {
    float t = acc[j] * inv;
    t = t > 0.f ? t : expm1f(t);   // elu
    nv[j] += t;
    bv[j] = f2bf(nv[j]);
  }
  *(f32x4*)(n_cur + i0) = nv;
  *(u16x4*)(n_bf + i0) = bv;
}

// ---- final-layer edge pass, ALL 8 heads: out_f = f_state + mean_h(y), exb per head ----
__global__ __launch_bounds__(256) void edge_final_all(
    int e0, int nech, const u16* __restrict__ t_ni, const u16* __restrict__ t_nj,
    const u16* __restrict__ fWc, const int* __restrict__ src, const int* __restrict__ dst,
    const float* __restrict__ bias, const float* __restrict__ attn,
    const u16* __restrict__ f_bf, float* __restrict__ out_f, float* __restrict__ exb) {
  int ec = blockIdx.x * 4 + (threadIdx.x >> 6);
  if (ec >= nech) return;
  int e = e0 + ec;
  int lane = threadIdx.x & 63;
  int is = src[e], id = dst[e];
  int c = lane * 4;
  float total[4] = {0.f, 0.f, 0.f, 0.f};
#pragma unroll
  for (int h = 0; h < 8; ++h) {
    u16x4 va = *(const u16x4*)(t_ni + (size_t)is * 2048 + h * 256 + c);
    u16x4 vb = *(const u16x4*)(t_nj + (size_t)id * 2048 + h * 256 + c);
    u16x4 vc = *(const u16x4*)(fWc + (size_t)ec * 2048 + h * 256 + c);
    f32x4 vbi = *(const f32x4*)(bias + h * 256 + c);
    f32x4 vat = *(const f32x4*)(attn + h * 256 + c);
    float part = 0.f;
#pragma unroll
    for (int j = 0; j < 4; ++j) {
      float y = bf2f(va[j]) + bf2f(vb[j]) + bf2f(vc[j]) + vbi[j];
      y = y > 0.f ? y : 0.01f * y;   // leaky_relu; final: head-mean, no elu
      part += y * vat[j];
      total[j] += 0.125f * y;
    }
#pragma unroll
    for (int m = 1; m < 64; m <<= 1) part += __shfl_xor(part, m);
    part = fminf(fmaxf(part, -30.f), 30.f);
    if (lane == 0) exb[(size_t)e * 8 + h] = expf(part);
  }
  size_t i0 = (size_t)e * 256 + c;
  u16x4 fs = *(const u16x4*)(f_bf + i0);
  f32x4 o;
#pragma unroll
  for (int j = 0; j < 4; ++j) o[j] = bf2f(fs[j]) + total[j];
  *(f32x4*)(out_f + i0) = o;
}

// ---- final gather, ALL 8 heads, p-outer/h-inner one-pass ----
__global__ __launch_bounds__(256) void node_gather_final_all(
    const u16* __restrict__ t_node, const int* __restrict__ row_ptr,
    const int* __restrict__ cs_e, const int* __restrict__ cs_src,
    const float* __restrict__ exb, const float* __restrict__ n_cur,
    float* __restrict__ out_n) {
  int node = blockIdx.x * 4 + (threadIdx.x >> 6);
  if (node >= NN) return;
  int lane = threadIdx.x & 63;
  int c = lane * 4;
  int beg = row_ptr[node], end = row_ptr[node + 1];
  float dh[8] = {};
  float acc[8][4] = {};
  for (int p = beg; p < end; ++p) {
    int e = cs_e[p];
    int s = cs_src[p];
    const u16* rowb = t_node + (size_t)s * 2048;
    const float* eb = exb + (size_t)e * 8;
    float a[8];
    u16x4 rv[8];
#pragma unroll
    for (int h = 0; h < 8; ++h) {
      a[h] = eb[h];
      rv[h] = *(const u16x4*)(rowb + h * 256 + c);   // 8 independent loads in flight
    }
#pragma unroll
    for (int h = 0; h < 8; ++h) {
      dh[h] += a[h];
#pragma unroll
      for (int j = 0; j < 4; ++j) acc[h][j] += a[h] * bf2f(rv[h][j]);
    }
  }
  float total[4] = {0.f, 0.f, 0.f, 0.f};
#pragma unroll
  for (int h = 0; h < 8; ++h) {
    float inv = dh[h] > 0.f ? 0.125f / dh[h] : 0.f;
#pragma unroll
    for (int j = 0; j < 4; ++j) total[j] += acc[h][j] * inv;
  }
  size_t i0 = (size_t)node * 256 + c;
  f32x4 nv = *(const f32x4*)(n_cur + i0);
#pragma unroll
  for (int j = 0; j < 4; ++j) nv[j] += total[j];
  *(f32x4*)(out_n + i0) = nv;
}

extern "C" void kernel_launch(void* const* d_in, const int* in_sizes, int n_in,
                              void* d_out, int out_size, void* d_ws, size_t ws_size,
                              hipStream_t stream) {
  const float* nfeat   = (const float*)d_in[0];
  const float* efeat   = (const float*)d_in[1];
  const int*   src     = (const int*)d_in[2];
  const int*   dst     = (const int*)d_in[3];
  const float* Wnode_h = (const float*)d_in[4];
  const float* Wni_h   = (const float*)d_in[5];
  const float* Wnj_h   = (const float*)d_in[6];
  const float* Wfij_h  = (const float*)d_in[7];
  const float* attn_h  = (const float*)d_in[8];
  const float* bias_h  = (const float*)d_in[9];
  const float* Wnode_l = (const float*)d_in[10];
  const float* Wni_l   = (const float*)d_in[11];
  const float* Wnj_l   = (const float*)d_in[12];
  const float* Wfij_l  = (const float*)d_in[13];
  const float* attn_l  = (const float*)d_in[14];
  const float* bias_l  = (const float*)d_in[15];

  char* ws = (char*)d_ws;
  size_t off = 0;
  auto alloc = [&](size_t b) { char* p = ws + off; off += (b + 255) & ~(size_t)255; return p; };
  float* n_cur = (float*)alloc((size_t)NN * 256 * 4);     // node state (f32)
  u16* n_bf    = (u16*)alloc((size_t)NN * 256 * 2);       // bf16 mirror (GEMM A)
  u16* f_bf    = (u16*)alloc((size_t)NE * 256 * 2);       // edge state (bf16)
  u16* t_ni    = (u16*)alloc((size_t)NN * 2048 * 2);      // final-layer node tables [NN,2048]
  u16* t_nj    = (u16*)alloc((size_t)NN * 2048 * 2);
  u16* t_node  = (u16*)alloc((size_t)NN * 2048 * 2);
  float* exb   = (float*)alloc((size_t)NE * 8 * 4);       // exp(logits)
  u16* WT      = (u16*)alloc((size_t)4 * 65536 * 2);      // hidden transposed weights
  u16* WTF     = (u16*)alloc((size_t)4 * 524288 * 2);     // final transposed weights
  int* deg     = (int*)alloc((size_t)NN * 4);             // CSR
  int* cursor  = (int*)alloc((size_t)NN * 4);
  int* row_ptr = (int*)alloc((size_t)(NN + 1) * 4);
  int* cs_e    = (int*)alloc((size_t)NE * 4);
  int* cs_src  = (int*)alloc((size_t)NE * 4);
  // fW last: chunk size adapts to available workspace (runtime-guarded)
  int ech;
  u16* fW;
  size_t fw_big = (size_t)16000 * 2048 * 2;   // 65.5 MB -> 4 chunks
  size_t fw_small = (size_t)NE * 256 * 2;     // 32.8 MB (hidden) >= 6400*2048*2
  if (off + fw_big <= ws_size) { ech = 16000; fW = (u16*)alloc(fw_big); }
  else                         { ech = 6400;  fW = (u16*)alloc(fw_small); }

  u16* WT_node = WT;
  u16* WT_ni   = WT + 65536;
  u16* WT_nj   = WT + 2 * 65536;
  u16* WT_fij  = WT + 3 * 65536;
  u16* WTF_node = WTF;
  u16* WTF_ni   = WTF + (size_t)1 * 524288;
  u16* WTF_nj   = WTF + (size_t)2 * 524288;
  u16* WTF_fij  = WTF + (size_t)3 * 524288;

  float* out_n = (float*)d_out;
  float* out_f = out_n + (size_t)NN * 256;

  // CSR build (reused by all message passes)
  hipMemsetAsync(deg, 0, (size_t)NN * 4, stream);
  deg_hist<<<(NE + 255) / 256, 256, 0, stream>>>(dst, deg);
  scan_deg<<<1, 1024, 0, stream>>>(deg, row_ptr, cursor);
  csr_fill<<<(NE + 255) / 256, 256, 0, stream>>>(src, dst, cursor, cs_e, cs_src);

  cast_init<<<1024, 256, 0, stream>>>(nfeat, n_cur, n_bf, NN * 256 / 4);
  cast_bf<<<2048, 256, 0, stream>>>(efeat, f_bf, NE * 256 / 4);

  // hidden layers (t_ni/t_nj/t_node used as [NN,256] tables here)
  for (int l = 0; l < 2; ++l) {
    transpose4<<<dim3(16, 16, 4), dim3(16, 16), 0, stream>>>(
        Wnode_h + (size_t)l * 65536, Wni_h + (size_t)l * 65536,
        Wnj_h + (size_t)l * 65536, Wfij_h + (size_t)l * 65536, 256, 65536, WT);
    gemm_abt<<<dim3(2, 125, 3), 256, 0, stream>>>(n_bf, WT_ni, WT_nj, WT_node,
                                                  t_ni, t_nj, t_node, 256);
    gemm_abt<<<dim3(2, 500, 1), 256, 0, stream>>>(f_bf, WT_fij, WT_fij, WT_fij,
                                                  fW, fW, fW, 256);
    edge_hidden<<<16000, 256, 0, stream>>>(t_ni, t_nj, fW, src, dst,
        bias_h + (size_t)l * 256, attn_h + (size_t)l * 256, f_bf, exb);
    node_gather_hidden<<<4000, 256, 0, stream>>>(t_node, row_ptr, cs_e, cs_src, exb, n_cur, n_bf);
  }

  // final layer: full-width node tables once, then edge-chunked f-GEMM + all-heads edge pass
  transpose4<<<dim3(128, 16, 4), dim3(16, 16), 0, stream>>>(
      Wnode_l, Wni_l, Wnj_l, Wfij_l, 2048, 524288, WTF);
  gemm_abt<<<dim3(16, 125, 3), 256, 0, stream>>>(n_bf, WTF_ni, WTF_nj, WTF_node,
                                                 t_ni, t_nj, t_node, 2048);
  for (int e0 = 0; e0 < NE; e0 += ech) {
    const u16* Ac = f_bf + (size_t)e0 * 256;
    gemm_abt<<<dim3(16, ech / 128, 1), 256, 0, stream>>>(Ac, WTF_fij, WTF_fij, WTF_fij,
                                                         fW, fW, fW, 2048);
    edge_final_all<<<ech / 4, 256, 0, stream>>>(e0, ech, t_ni, t_nj, fW, src, dst,
                                                bias_l, attn_l, f_bf, out_f, exb);
  }
  node_gather_final_all<<<4000, 256, 0, stream>>>(t_node, row_ptr, cs_e, cs_src,
                                                  exb, n_cur, out_n);
}